// Round 11
// baseline (303.998 us; speedup 1.0000x reference)
//
#include <hip/hip_runtime.h>
#include <hip/hip_bf16.h>
#include <cstdint>

typedef __attribute__((ext_vector_type(8))) short bf16x8;
typedef __attribute__((ext_vector_type(4))) short bf16x4;
typedef __attribute__((ext_vector_type(4))) float f32x4;

#define B_SZ 8192
#define TROW 3456   // 27*128, per-sample stride of T buffer (bf16 elems)

__device__ __forceinline__ void gld_lds16(const void* g, void* l) {
    __builtin_amdgcn_global_load_lds(
        (const __attribute__((address_space(1))) unsigned int*)g,
        (__attribute__((address_space(3))) unsigned int*)l, 16, 0, 0);
}

__device__ __forceinline__ short f2bf_bits(float v) {
    return __builtin_bit_cast(short, __float2bfloat16(v));
}

// ---------------- weight cvt (8 elems/thread) ----------------
struct CvtJob { const float* in; __hip_bfloat16* out; int N, K, Kp; };
struct CvtJobs { CvtJob j[6]; int start[7]; };   // starts in ELEMENTS (all sizes %8==0)

__device__ __forceinline__ void cvt_dev8(int lb, int tid, const CvtJobs& J) {
    int chunk = lb * 256 + tid;
    int e = chunk * 8;
    if (e >= J.start[6]) return;
    int k = 0;
    #pragma unroll
    for (int i = 1; i < 6; i++) if (e >= J.start[i]) k = i;
    const CvtJob& job = J.j[k];
    int local = e - J.start[k];
    float v[8];
    if (job.K == job.Kp) {
        const float4* p = (const float4*)(job.in + local);
        float4 a = p[0], b = p[1];
        v[0]=a.x; v[1]=a.y; v[2]=a.z; v[3]=a.w; v[4]=b.x; v[5]=b.y; v[6]=b.z; v[7]=b.w;
    } else {
        int n = local / job.Kp, kk = local - n * job.Kp;
        #pragma unroll
        for (int i = 0; i < 8; i++)
            v[i] = (kk + i < job.K) ? job.in[(size_t)n * job.K + kk + i] : 0.f;
    }
    bf16x8 o;
    #pragma unroll
    for (int i = 0; i < 8; i++)
        o[i] = f2bf_bits(v[i]);
    *(bf16x8*)(job.out + local) = o;
}

// ---------------- bot0 fp32 (K=13) ----------------
__device__ __forceinline__ void bot0_dev(int lb, int tid, const float* __restrict__ x,
    const float* __restrict__ w, const float* __restrict__ bias,
    __hip_bfloat16* __restrict__ o, float* xs) {
    int m0 = lb * 4;
    if (tid < 52) xs[tid] = x[(size_t)m0 * 13 + tid];
    __syncthreads();
    for (int c = tid; c < 512; c += 256) {
        const float* wr = w + (size_t)c * 13;
        float bv = bias[c];
        #pragma unroll
        for (int r = 0; r < 4; r++) {
            float s = bv;
            #pragma unroll
            for (int k = 0; k < 13; k++) s += xs[r * 13 + k] * wr[k];
            o[(size_t)(m0 + r) * 512 + c] = __float2bfloat16(fmaxf(s, 0.f));
        }
    }
}

// ---------------- embedding gather-sum (16B/lane, table slice from t0) ----------------
__device__ __forceinline__ void emb_dev(int lb, int tid, int t0,
    const int* __restrict__ idx, const float* __restrict__ tab,
    __hip_bfloat16* __restrict__ T) {
    int lane = tid & 63, wv = tid >> 6;
    int p = lb * 4 + wv;
    int t = t0 + (p >> 13);
    int b = p & 8191;
    const int* ip = idx + (size_t)t * 81920 + b * 10;
    const float* tb = tab + (size_t)t * 100000 * 128;
    int half = lane >> 5, l32 = lane & 31;
    float4 s = {0.f, 0.f, 0.f, 0.f};
    #pragma unroll
    for (int j = 0; j < 10; j += 2) {
        int r = ip[j + half];
        float4 v = ((const float4*)(tb + (size_t)r * 128))[l32];
        s.x += v.x; s.y += v.y; s.z += v.z; s.w += v.w;
    }
    s.x += __shfl_xor(s.x, 32, 64);
    s.y += __shfl_xor(s.y, 32, 64);
    s.z += __shfl_xor(s.z, 32, 64);
    s.w += __shfl_xor(s.w, 32, 64);
    if (half == 0) {
        bf16x4 o;
        o[0] = f2bf_bits(s.x); o[1] = f2bf_bits(s.y);
        o[2] = f2bf_bits(s.z); o[3] = f2bf_bits(s.w);
        ((bf16x4*)(T + (size_t)b * TROW + (1 + t) * 128))[l32] = o;
    }
}

// ---------------- GEMM device core: BK=64, XOR-swizzled LDS, packed C-write ----------------
template<int TM, int TN, int WM, int WN>
__device__ __forceinline__ void gemm_dev(int tileId, int nTiles, int nbx, int tid,
    const __hip_bfloat16* __restrict__ A, const __hip_bfloat16* __restrict__ W,
    const float* __restrict__ bias, __hip_bfloat16* __restrict__ C,
    int K, int ldc, __hip_bfloat16* ABs) {
    constexpr int BK = 64;
    constexpr int ROWS = TM + TN;
    constexpr int CH = ROWS * BK / 2048;      // 4KB (32-row) chunks per K-step
    constexpr int MI = TM / WM / 16;
    constexpr int NI = TN / WN / 16;

    // XCD-bijective swizzle: blocks sharing an A-panel land on one XCD
    int swz = tileId;
    if ((nTiles & 7) == 0) {
        int q = nTiles >> 3;
        swz = (tileId & 7) * q + (tileId >> 3);
    }
    const int by = swz / nbx, bx = swz - by * nbx;
    const int m0 = by * TM, n0 = bx * TN;

    const int lane = tid & 63, wave = tid >> 6;
    const int wmI = wave / WN, wnI = wave % WN;

    const __hip_bfloat16* gp[CH];
    #pragma unroll
    for (int c = 0; c < CH; c++) {
        int gid = c * 256 + tid;
        int row = gid >> 3;                          // 8 x 16B chunks per 64-elem row
        int cs = ((gid & 7) ^ (row & 7)) * 8;        // pre-swizzled source column
        gp[c] = (row < TM ? A + (size_t)(m0 + row) * K
                          : W + (size_t)(n0 + row - TM) * K) + cs;
    }

    f32x4 acc[MI][NI] = {};
    const int fr = lane & 15, hi = lane >> 4;

    for (int k0 = 0; k0 < K; k0 += BK) {
        __syncthreads();
        #pragma unroll
        for (int c = 0; c < CH; c++)
            gld_lds16(gp[c] + k0, &ABs[(c * 256 + wave * 64) * 8]);
        asm volatile("s_waitcnt vmcnt(0)" ::: "memory");
        __syncthreads();
        #pragma unroll
        for (int ks = 0; ks < 2; ks++) {
            bf16x8 a[MI], b[NI];
            #pragma unroll
            for (int i = 0; i < MI; i++) {
                int row = wmI * (TM / WM) + i * 16 + fr;
                a[i] = *(const bf16x8*)&ABs[row * BK + (((ks * 4 + hi) ^ (row & 7)) * 8)];
            }
            #pragma unroll
            for (int j = 0; j < NI; j++) {
                int row = TM + wnI * (TN / WN) + j * 16 + fr;
                b[j] = *(const bf16x8*)&ABs[row * BK + (((ks * 4 + hi) ^ (row & 7)) * 8)];
            }
            #pragma unroll
            for (int i = 0; i < MI; i++)
                #pragma unroll
                for (int j = 0; j < NI; j++)
                    acc[i][j] = __builtin_amdgcn_mfma_f32_16x16x32_bf16(a[i], b[j], acc[i][j], 0, 0, 0);
        }
    }

    // packed epilogue: pair adjacent cols via shfl_xor(1) -> u32 stores
    const int fq = hi;
    const bool evenL = (fr & 1) == 0;
    #pragma unroll
    for (int i = 0; i < MI; i++) {
        #pragma unroll
        for (int j = 0; j < NI; j++) {
            int n = n0 + wnI * (TN / WN) + j * 16 + fr;
            float bv = bias[n];
            float v[4];
            #pragma unroll
            for (int r = 0; r < 4; r++)
                v[r] = fmaxf(acc[i][j][r] + bv, 0.f);
            #pragma unroll
            for (int r = 0; r < 4; r++) {
                float pv = __shfl_xor(v[r], 1, 64);
                // even lane stores rows r=0,1 (cols fr,fr+1); odd lane rows r=2,3 (cols fr-1,fr)
                if ((r < 2) == evenL) {
                    unsigned lo = (unsigned short)(evenL ? f2bf_bits(v[r]) : f2bf_bits(pv));
                    unsigned hiv = (unsigned short)(evenL ? f2bf_bits(pv) : f2bf_bits(v[r]));
                    unsigned pack = lo | (hiv << 16);
                    int m = m0 + wmI * (TM / WM) + i * 16 + fq * 4 + r;
                    int nn = n & ~1;
                    *(unsigned*)&C[(size_t)m * ldc + nn] = pack;
                }
            }
        }
    }
}

// standalone GEMM wrapper (1-D grid of tiles)
template<int TM, int TN, int WM, int WN>
__global__ __launch_bounds__(256) void gemm_k(const __hip_bfloat16* A, const __hip_bfloat16* W,
                                              const float* bias, __hip_bfloat16* C,
                                              int nbx, int K, int ldc) {
    __shared__ __align__(16) __hip_bfloat16 ABs[(TM + TN) * 64];
    gemm_dev<TM, TN, WM, WN>(blockIdx.x, gridDim.x, nbx, threadIdx.x, A, W, bias, C, K, ldc, ABs);
}

// L1: cvt || bot0 || emb(tables t0..)
__global__ __launch_bounds__(256) void k_pre_emb(CvtJobs J, int cvtB,
    const float* dx, const float* w0, const float* b0, __hip_bfloat16* bufA,
    int t0, const int* sidx, const float* tab, __hip_bfloat16* T) {
    __shared__ float xs[64];
    int blk = blockIdx.x, tid = threadIdx.x;
    if (blk < cvtB) { cvt_dev8(blk, tid, J); return; }
    blk -= cvtB;
    if (blk < B_SZ / 4) { bot0_dev(blk, tid, dx, w0, b0, bufA, xs); return; }
    emb_dev(blk - B_SZ / 4, tid, t0, sidx, tab, T);
}

// gemm || emb(tables t0..)
template<int TM, int TN>
__global__ __launch_bounds__(256) void k_gemm_emb(const __hip_bfloat16* A, const __hip_bfloat16* W,
    const float* bias, __hip_bfloat16* C, int nbx, int K, int ldc, int gB,
    int t0, const int* sidx, const float* tab, __hip_bfloat16* T) {
    __shared__ __align__(16) __hip_bfloat16 ABs[(TM + TN) * 64];
    if (blockIdx.x < gB)
        gemm_dev<TM, TN, 2, 2>(blockIdx.x, gB, nbx, threadIdx.x, A, W, bias, C, K, ldc, ABs);
    else
        emb_dev(blockIdx.x - gB, threadIdx.x, t0, sidx, tab, T);
}

// ---------------- interaction (LDS-free): 4 samples/block ----------------
__global__ __launch_bounds__(256) void k_int(const __hip_bfloat16* __restrict__ T,
                                             __hip_bfloat16* __restrict__ z) {
    int lane = threadIdx.x & 63, wave = threadIdx.x >> 6;
    int b = blockIdx.x * 4 + wave;
    const __hip_bfloat16* Tb = T + (size_t)b * TROW;

    const int fr = lane & 15, fkb = (lane >> 4) * 8;
    bf16x8 fr2[2][4];
    #pragma unroll
    for (int mi = 0; mi < 2; mi++)
        #pragma unroll
        for (int kt = 0; kt < 4; kt++)
            fr2[mi][kt] = *(const bf16x8*)&Tb[(mi * 16 + fr) * 128 + kt * 32 + fkb];

    f32x4 acc[2][2] = {};
    #pragma unroll
    for (int kt = 0; kt < 4; kt++)
        #pragma unroll
        for (int mi = 0; mi < 2; mi++)
            #pragma unroll
            for (int ni = 0; ni < 2; ni++)
                acc[mi][ni] = __builtin_amdgcn_mfma_f32_16x16x32_bf16(fr2[mi][kt], fr2[ni][kt], acc[mi][ni], 0, 0, 0);

    __hip_bfloat16* zb = z + (size_t)b * 512;
    ((unsigned*)zb)[lane] = ((const unsigned*)Tb)[lane];       // copy x row (128 bf16)
    if (lane < 33) zb[479 + lane] = __float2bfloat16(0.f);     // pad cols 479..511
    const int fq = lane >> 4;
    #pragma unroll
    for (int mi = 0; mi < 2; mi++)
        #pragma unroll
        for (int ni = 0; ni < 2; ni++)
            #pragma unroll
            for (int r = 0; r < 4; r++) {
                int m = mi * 16 + fq * 4 + r;
                int n = ni * 16 + fr;
                if (m < 27 && n < 27 && m < n) {
                    int p = m * 26 - (m * (m - 1)) / 2 + (n - m - 1);
                    zb[128 + p] = __float2bfloat16(acc[mi][ni][r]);
                }
            }
}

// ---------------- fused top3+final: TM=32 rows/block (256 blocks = 1/CU), K=512, BK=32 ----------------
// LDS rows: 0..255 = W (256 x 512), 256..287 = A rows m0..m0+31.
__global__ __launch_bounds__(256) void k_top3_fin(const __hip_bfloat16* __restrict__ A,
                                                  const __hip_bfloat16* __restrict__ W,
                                                  const float* __restrict__ b3,
                                                  const float* __restrict__ w4,
                                                  const float* __restrict__ b4,
                                                  float* __restrict__ out) {
    constexpr int TM = 32, TN = 256, K = 512;
    constexpr int ROWS = TM + TN;           // 288
    __shared__ __align__(16) __hip_bfloat16 ABs[ROWS * 32];
    __shared__ float red[4 * 32];

    const int tid = threadIdx.x;
    const int lane = tid & 63, wave = tid >> 6;   // wnI = wave (WM=1, WN=4)
    const int m0 = blockIdx.x * TM;

    // 16B chunks: 288 rows x 4 chunks = 1152; 5 chunk-passes, last one half-masked
    const __hip_bfloat16* gp[5];
    #pragma unroll
    for (int c = 0; c < 5; c++) {
        int gid = c * 256 + tid;
        int row = gid >> 2, col = (gid & 3) * 8;
        if (gid < 1152)
            gp[c] = (row < TN ? W + (size_t)row * K
                              : A + (size_t)(m0 + row - TN) * K) + col;
        else gp[c] = nullptr;
    }

    f32x4 acc[2][4] = {};
    const int fr = lane & 15, fkb = (lane >> 4) * 8;

    for (int k0 = 0; k0 < K; k0 += 32) {
        __syncthreads();
        #pragma unroll
        for (int c = 0; c < 5; c++)
            if (gp[c])
                gld_lds16(gp[c] + k0, &ABs[(c * 256 + wave * 64) * 8]);
        asm volatile("s_waitcnt vmcnt(0)" ::: "memory");
        __syncthreads();
        bf16x8 a[2], b[4];
        #pragma unroll
        for (int i = 0; i < 2; i++)
            a[i] = *(const bf16x8*)&ABs[(TN + i * 16 + fr) * 32 + fkb];
        #pragma unroll
        for (int j = 0; j < 4; j++)
            b[j] = *(const bf16x8*)&ABs[(wave * 64 + j * 16 + fr) * 32 + fkb];
        #pragma unroll
        for (int i = 0; i < 2; i++)
            #pragma unroll
            for (int j = 0; j < 4; j++)
                acc[i][j] = __builtin_amdgcn_mfma_f32_16x16x32_bf16(a[i], b[j], acc[i][j], 0, 0, 0);
    }

    // epilogue: per-lane partial of sum_n relu(acc + b3[n]) * w4[n]
    float p[2][4] = {};   // [i][r]
    #pragma unroll
    for (int j = 0; j < 4; j++) {
        int n = wave * 64 + j * 16 + fr;
        float bv = b3[n], wv = w4[n];
        #pragma unroll
        for (int i = 0; i < 2; i++)
            #pragma unroll
            for (int r = 0; r < 4; r++)
                p[i][r] += fmaxf(acc[i][j][r] + bv, 0.f) * wv;
    }
    #pragma unroll
    for (int mask = 1; mask < 16; mask <<= 1)
        #pragma unroll
        for (int i = 0; i < 2; i++)
            #pragma unroll
            for (int r = 0; r < 4; r++)
                p[i][r] += __shfl_xor(p[i][r], mask, 64);
    const int fq = lane >> 4;
    if (fr == 0) {
        #pragma unroll
        for (int i = 0; i < 2; i++)
            #pragma unroll
            for (int r = 0; r < 4; r++)
                red[wave * 32 + i * 16 + fq * 4 + r] = p[i][r];
    }
    __syncthreads();
    if (tid < 32) {
        float s = red[tid] + red[32 + tid] + red[64 + tid] + red[96 + tid];
        out[m0 + tid] = 1.f / (1.f + expf(-(s + b4[0])));
    }
}

extern "C" void kernel_launch(void* const* d_in, const int* in_sizes, int n_in,
                              void* d_out, int out_size, void* d_ws, size_t ws_size,
                              hipStream_t stream) {
    const float* dense_x = (const float*)d_in[0];
    const int* sidx      = (const int*)d_in[1];
    const float* emb     = (const float*)d_in[2];
    const float* bw0 = (const float*)d_in[3];  const float* bb0 = (const float*)d_in[4];
    const float* bw1 = (const float*)d_in[5];  const float* bb1 = (const float*)d_in[6];
    const float* bw2 = (const float*)d_in[7];  const float* bb2 = (const float*)d_in[8];
    const float* tw0 = (const float*)d_in[9];  const float* tb0 = (const float*)d_in[10];
    const float* tw1 = (const float*)d_in[11]; const float* tb1 = (const float*)d_in[12];
    const float* tw2 = (const float*)d_in[13]; const float* tb2 = (const float*)d_in[14];
    const float* tw3 = (const float*)d_in[15]; const float* tb3 = (const float*)d_in[16];
    const float* tw4 = (const float*)d_in[17]; const float* tb4 = (const float*)d_in[18];
    float* out = (float*)d_out;

    char* ws = (char*)d_ws;
    size_t off = 0;
    auto alloc = [&](size_t bytes) {
        off = (off + 255) & ~(size_t)255;
        void* p = ws + off;
        off += bytes;
        return p;
    };
    __hip_bfloat16* Wb1 = (__hip_bfloat16*)alloc((size_t)256 * 512 * 2);
    __hip_bfloat16* Wb2 = (__hip_bfloat16*)alloc((size_t)128 * 256 * 2);
    __hip_bfloat16* Wt0 = (__hip_bfloat16*)alloc((size_t)1024 * 512 * 2);
    __hip_bfloat16* Wt1 = (__hip_bfloat16*)alloc((size_t)1024 * 1024 * 2);
    __hip_bfloat16* Wt2 = (__hip_bfloat16*)alloc((size_t)512 * 1024 * 2);
    __hip_bfloat16* Wt3 = (__hip_bfloat16*)alloc((size_t)256 * 512 * 2);
    __hip_bfloat16* bufA = (__hip_bfloat16*)alloc((size_t)B_SZ * 512 * 2);
    __hip_bfloat16* bufB = (__hip_bfloat16*)alloc((size_t)B_SZ * 256 * 2);
    __hip_bfloat16* Tbuf = (__hip_bfloat16*)alloc((size_t)B_SZ * TROW * 2);
    __hip_bfloat16* zbuf = (__hip_bfloat16*)alloc((size_t)B_SZ * 512 * 2);
    __hip_bfloat16* h0   = (__hip_bfloat16*)alloc((size_t)B_SZ * 1024 * 2);
    __hip_bfloat16* h1   = (__hip_bfloat16*)alloc((size_t)B_SZ * 1024 * 2);
    __hip_bfloat16* h2   = (__hip_bfloat16*)alloc((size_t)B_SZ * 512 * 2);

    CvtJobs J;
    auto setJob = [&](int i, const float* in, __hip_bfloat16* o, int N, int K, int Kp) {
        J.j[i] = {in, o, N, K, Kp};
    };
    setJob(0, bw1, Wb1, 256, 512, 512);
    setJob(1, bw2, Wb2, 128, 256, 256);
    setJob(2, tw0, Wt0, 1024, 479, 512);
    setJob(3, tw1, Wt1, 1024, 1024, 1024);
    setJob(4, tw2, Wt2, 512, 1024, 1024);
    setJob(5, tw3, Wt3, 256, 512, 512);
    J.start[0] = 0;
    for (int i = 0; i < 6; i++) J.start[i + 1] = J.start[i] + J.j[i].N * J.j[i].Kp;
    const int cvtB = (J.start[6] / 8 + 255) / 256;
    const int EMB_T = B_SZ / 4;   // blocks per table

    // L1: weight cvt || bot0 || emb(tables 0..8)
    k_pre_emb<<<cvtB + B_SZ / 4 + 9 * EMB_T, 256, 0, stream>>>(
        J, cvtB, dense_x, bw0, bb0, bufA, 0, sidx, emb, Tbuf);

    // L2: bot1 (256 tiles, 128x64) || emb(tables 9..16)
    k_gemm_emb<128, 64><<<256 + 8 * EMB_T, 256, 0, stream>>>(
        bufA, Wb1, bb1, bufB, 256 / 64, 512, 256, 256, 9, sidx, emb, Tbuf);

    // L3: bot2 (256 tiles, 64x64) -> Tbuf row 0 || emb(tables 17..25)
    k_gemm_emb<64, 64><<<256 + 9 * EMB_T, 256, 0, stream>>>(
        bufB, Wb2, bb2, Tbuf, 128 / 64, 256, TROW, 256, 17, sidx, emb, Tbuf);

    // L4: interaction -> z (B x 512, padded)
    k_int<<<B_SZ / 4, 256, 0, stream>>>(Tbuf, zbuf);

    // L5-L7: top MLP, full-width, XCD-swizzled, BK=64 + LDS XOR swizzle + packed C-write
    gemm_k<128,128, 2, 2><<<(B_SZ / 128) * (1024 / 128), 256, 0, stream>>>(zbuf, Wt0, tb0, h0, 1024 / 128, 512, 1024);
    gemm_k<128,128, 2, 2><<<(B_SZ / 128) * (1024 / 128), 256, 0, stream>>>(h0, Wt1, tb1, h1, 1024 / 128, 1024, 1024);
    gemm_k<128,128, 2, 2><<<(B_SZ / 128) * ( 512 / 128), 256, 0, stream>>>(h1, Wt2, tb2, h2, 512 / 128, 1024, 512);

    // L8: fused top3 + final dot + sigmoid (256 blocks = 1/CU)
    k_top3_fin<<<B_SZ / 32, 256, 0, stream>>>(h2, Wt3, tb3, tw4, tb4, out);
}

// Round 12
// 297.973 us; speedup vs baseline: 1.0202x; 1.0202x over previous
//
#include <hip/hip_runtime.h>
#include <hip/hip_bf16.h>
#include <cstdint>

typedef __attribute__((ext_vector_type(8))) short bf16x8;
typedef __attribute__((ext_vector_type(4))) short bf16x4;
typedef __attribute__((ext_vector_type(4))) float f32x4;

#define B_SZ 8192
#define TROW 3456   // 27*128, per-sample stride of T buffer (bf16 elems)

__device__ __forceinline__ void gld_lds16(const void* g, void* l) {
    __builtin_amdgcn_global_load_lds(
        (const __attribute__((address_space(1))) unsigned int*)g,
        (__attribute__((address_space(3))) unsigned int*)l, 16, 0, 0);
}

__device__ __forceinline__ short f2bf_bits(float v) {
    return __builtin_bit_cast(short, __float2bfloat16(v));
}

// ---------------- weight cvt (8 elems/thread) ----------------
struct CvtJob { const float* in; __hip_bfloat16* out; int N, K, Kp; };
struct CvtJobs { CvtJob j[6]; int start[7]; };   // starts in ELEMENTS (all sizes %8==0)

__device__ __forceinline__ void cvt_dev8(int lb, int tid, const CvtJobs& J) {
    int chunk = lb * 256 + tid;
    int e = chunk * 8;
    if (e >= J.start[6]) return;
    int k = 0;
    #pragma unroll
    for (int i = 1; i < 6; i++) if (e >= J.start[i]) k = i;
    const CvtJob& job = J.j[k];
    int local = e - J.start[k];
    float v[8];
    if (job.K == job.Kp) {
        const float4* p = (const float4*)(job.in + local);
        float4 a = p[0], b = p[1];
        v[0]=a.x; v[1]=a.y; v[2]=a.z; v[3]=a.w; v[4]=b.x; v[5]=b.y; v[6]=b.z; v[7]=b.w;
    } else {
        int n = local / job.Kp, kk = local - n * job.Kp;
        #pragma unroll
        for (int i = 0; i < 8; i++)
            v[i] = (kk + i < job.K) ? job.in[(size_t)n * job.K + kk + i] : 0.f;
    }
    bf16x8 o;
    #pragma unroll
    for (int i = 0; i < 8; i++)
        o[i] = f2bf_bits(v[i]);
    *(bf16x8*)(job.out + local) = o;
}

// ---------------- bot0 fp32 (K=13) ----------------
__device__ __forceinline__ void bot0_dev(int lb, int tid, const float* __restrict__ x,
    const float* __restrict__ w, const float* __restrict__ bias,
    __hip_bfloat16* __restrict__ o, float* xs) {
    int m0 = lb * 4;
    if (tid < 52) xs[tid] = x[(size_t)m0 * 13 + tid];
    __syncthreads();
    for (int c = tid; c < 512; c += 256) {
        const float* wr = w + (size_t)c * 13;
        float bv = bias[c];
        #pragma unroll
        for (int r = 0; r < 4; r++) {
            float s = bv;
            #pragma unroll
            for (int k = 0; k < 13; k++) s += xs[r * 13 + k] * wr[k];
            o[(size_t)(m0 + r) * 512 + c] = __float2bfloat16(fmaxf(s, 0.f));
        }
    }
}

// ---------------- embedding gather-sum (16B/lane, table slice from t0) ----------------
__device__ __forceinline__ void emb_dev(int lb, int tid, int t0,
    const int* __restrict__ idx, const float* __restrict__ tab,
    __hip_bfloat16* __restrict__ T) {
    int lane = tid & 63, wv = tid >> 6;
    int p = lb * 4 + wv;
    int t = t0 + (p >> 13);
    int b = p & 8191;
    const int* ip = idx + (size_t)t * 81920 + b * 10;
    const float* tb = tab + (size_t)t * 100000 * 128;
    int half = lane >> 5, l32 = lane & 31;
    float4 s = {0.f, 0.f, 0.f, 0.f};
    #pragma unroll
    for (int j = 0; j < 10; j += 2) {
        int r = ip[j + half];
        float4 v = ((const float4*)(tb + (size_t)r * 128))[l32];
        s.x += v.x; s.y += v.y; s.z += v.z; s.w += v.w;
    }
    s.x += __shfl_xor(s.x, 32, 64);
    s.y += __shfl_xor(s.y, 32, 64);
    s.z += __shfl_xor(s.z, 32, 64);
    s.w += __shfl_xor(s.w, 32, 64);
    if (half == 0) {
        bf16x4 o;
        o[0] = f2bf_bits(s.x); o[1] = f2bf_bits(s.y);
        o[2] = f2bf_bits(s.z); o[3] = f2bf_bits(s.w);
        ((bf16x4*)(T + (size_t)b * TROW + (1 + t) * 128))[l32] = o;
    }
}

// ---------------- GEMM device core: BK=64, XOR-swizzled LDS (rule #21 compliant) ----------------
// staging: linear LDS dest; per-lane global source chunk pre-swizzled (chunk ^= row&7).
// read: same XOR on the chunk index -> uniform 8-lanes-per-4-bank access.
template<int TM, int TN, int WM, int WN>
__device__ __forceinline__ void gemm_dev(int tileId, int nTiles, int nbx, int tid,
    const __hip_bfloat16* __restrict__ A, const __hip_bfloat16* __restrict__ W,
    const float* __restrict__ bias, __hip_bfloat16* __restrict__ C,
    int K, int ldc, __hip_bfloat16* ABs) {
    constexpr int BK = 64;
    constexpr int ROWS = TM + TN;
    constexpr int CH = ROWS * BK / 2048;      // 4KB (32-row) chunks per K-step
    constexpr int MI = TM / WM / 16;
    constexpr int NI = TN / WN / 16;

    // XCD-bijective swizzle: blocks sharing an A-panel land on one XCD
    int swz = tileId;
    if ((nTiles & 7) == 0) {
        int q = nTiles >> 3;
        swz = (tileId & 7) * q + (tileId >> 3);
    }
    const int by = swz / nbx, bx = swz - by * nbx;
    const int m0 = by * TM, n0 = bx * TN;

    const int lane = tid & 63, wave = tid >> 6;
    const int wmI = wave / WN, wnI = wave % WN;

    const __hip_bfloat16* gp[CH];
    #pragma unroll
    for (int c = 0; c < CH; c++) {
        int gid = c * 256 + tid;
        int row = gid >> 3;                          // 8 x 16B chunks per 64-elem row
        int cs = ((gid & 7) ^ (row & 7)) * 8;        // pre-swizzled source column
        gp[c] = (row < TM ? A + (size_t)(m0 + row) * K
                          : W + (size_t)(n0 + row - TM) * K) + cs;
    }

    f32x4 acc[MI][NI] = {};
    const int fr = lane & 15, hi = lane >> 4;

    for (int k0 = 0; k0 < K; k0 += BK) {
        __syncthreads();
        #pragma unroll
        for (int c = 0; c < CH; c++)
            gld_lds16(gp[c] + k0, &ABs[(c * 256 + wave * 64) * 8]);
        asm volatile("s_waitcnt vmcnt(0)" ::: "memory");
        __syncthreads();
        #pragma unroll
        for (int ks = 0; ks < 2; ks++) {
            bf16x8 a[MI], b[NI];
            #pragma unroll
            for (int i = 0; i < MI; i++) {
                int row = wmI * (TM / WM) + i * 16 + fr;
                a[i] = *(const bf16x8*)&ABs[row * BK + (((ks * 4 + hi) ^ (row & 7)) * 8)];
            }
            #pragma unroll
            for (int j = 0; j < NI; j++) {
                int row = TM + wnI * (TN / WN) + j * 16 + fr;
                b[j] = *(const bf16x8*)&ABs[row * BK + (((ks * 4 + hi) ^ (row & 7)) * 8)];
            }
            #pragma unroll
            for (int i = 0; i < MI; i++)
                #pragma unroll
                for (int j = 0; j < NI; j++)
                    acc[i][j] = __builtin_amdgcn_mfma_f32_16x16x32_bf16(a[i], b[j], acc[i][j], 0, 0, 0);
        }
    }

    const int fq = hi;
    #pragma unroll
    for (int i = 0; i < MI; i++) {
        #pragma unroll
        for (int j = 0; j < NI; j++) {
            int n = n0 + wnI * (TN / WN) + j * 16 + fr;
            float bv = bias[n];
            #pragma unroll
            for (int r = 0; r < 4; r++) {
                int m = m0 + wmI * (TM / WM) + i * 16 + fq * 4 + r;
                C[(size_t)m * ldc + n] = __float2bfloat16(fmaxf(acc[i][j][r] + bv, 0.f));
            }
        }
    }
}

// standalone GEMM wrapper (1-D grid of tiles)
template<int TM, int TN, int WM, int WN>
__global__ __launch_bounds__(256) void gemm_k(const __hip_bfloat16* A, const __hip_bfloat16* W,
                                              const float* bias, __hip_bfloat16* C,
                                              int nbx, int K, int ldc) {
    __shared__ __align__(16) __hip_bfloat16 ABs[(TM + TN) * 64];
    gemm_dev<TM, TN, WM, WN>(blockIdx.x, gridDim.x, nbx, threadIdx.x, A, W, bias, C, K, ldc, ABs);
}

// L1: cvt || bot0 || emb(tables t0..)
__global__ __launch_bounds__(256) void k_pre_emb(CvtJobs J, int cvtB,
    const float* dx, const float* w0, const float* b0, __hip_bfloat16* bufA,
    int t0, const int* sidx, const float* tab, __hip_bfloat16* T) {
    __shared__ float xs[64];
    int blk = blockIdx.x, tid = threadIdx.x;
    if (blk < cvtB) { cvt_dev8(blk, tid, J); return; }
    blk -= cvtB;
    if (blk < B_SZ / 4) { bot0_dev(blk, tid, dx, w0, b0, bufA, xs); return; }
    emb_dev(blk - B_SZ / 4, tid, t0, sidx, tab, T);
}

// gemm || emb(tables t0..)
template<int TM, int TN>
__global__ __launch_bounds__(256) void k_gemm_emb(const __hip_bfloat16* A, const __hip_bfloat16* W,
    const float* bias, __hip_bfloat16* C, int nbx, int K, int ldc, int gB,
    int t0, const int* sidx, const float* tab, __hip_bfloat16* T) {
    __shared__ __align__(16) __hip_bfloat16 ABs[(TM + TN) * 64];
    if (blockIdx.x < gB)
        gemm_dev<TM, TN, 2, 2>(blockIdx.x, gB, nbx, threadIdx.x, A, W, bias, C, K, ldc, ABs);
    else
        emb_dev(blockIdx.x - gB, threadIdx.x, t0, sidx, tab, T);
}

// ---------------- interaction (LDS-free): 4 samples/block ----------------
__global__ __launch_bounds__(256) void k_int(const __hip_bfloat16* __restrict__ T,
                                             __hip_bfloat16* __restrict__ z) {
    int lane = threadIdx.x & 63, wave = threadIdx.x >> 6;
    int b = blockIdx.x * 4 + wave;
    const __hip_bfloat16* Tb = T + (size_t)b * TROW;

    const int fr = lane & 15, fkb = (lane >> 4) * 8;
    bf16x8 fr2[2][4];
    #pragma unroll
    for (int mi = 0; mi < 2; mi++)
        #pragma unroll
        for (int kt = 0; kt < 4; kt++)
            fr2[mi][kt] = *(const bf16x8*)&Tb[(mi * 16 + fr) * 128 + kt * 32 + fkb];

    f32x4 acc[2][2] = {};
    #pragma unroll
    for (int kt = 0; kt < 4; kt++)
        #pragma unroll
        for (int mi = 0; mi < 2; mi++)
            #pragma unroll
            for (int ni = 0; ni < 2; ni++)
                acc[mi][ni] = __builtin_amdgcn_mfma_f32_16x16x32_bf16(fr2[mi][kt], fr2[ni][kt], acc[mi][ni], 0, 0, 0);

    __hip_bfloat16* zb = z + (size_t)b * 512;
    ((unsigned*)zb)[lane] = ((const unsigned*)Tb)[lane];       // copy x row (128 bf16)
    if (lane < 33) zb[479 + lane] = __float2bfloat16(0.f);     // pad cols 479..511
    const int fq = lane >> 4;
    #pragma unroll
    for (int mi = 0; mi < 2; mi++)
        #pragma unroll
        for (int ni = 0; ni < 2; ni++)
            #pragma unroll
            for (int r = 0; r < 4; r++) {
                int m = mi * 16 + fq * 4 + r;
                int n = ni * 16 + fr;
                if (m < 27 && n < 27 && m < n) {
                    int p = m * 26 - (m * (m - 1)) / 2 + (n - m - 1);
                    zb[128 + p] = __float2bfloat16(acc[mi][ni][r]);
                }
            }
}

// ---------------- fused top3+final: h3 = relu(h2 @ W3^T + b3); out = sigmoid(h3 . w4 + b4) ----------------
// TM=64 rows/block, TN=256 (full layer width), K=512, BK=32. Grid = 128 blocks.
__global__ __launch_bounds__(256) void k_top3_fin(const __hip_bfloat16* __restrict__ A,
                                                  const __hip_bfloat16* __restrict__ W,
                                                  const float* __restrict__ b3,
                                                  const float* __restrict__ w4,
                                                  const float* __restrict__ b4,
                                                  float* __restrict__ out) {
    constexpr int TM = 64, TN = 256, K = 512;
    constexpr int ROWS = TM + TN;           // 320
    constexpr int CH = ROWS * 4 / 256;      // 5
    __shared__ __align__(16) __hip_bfloat16 ABs[ROWS * 32];
    __shared__ float red[4 * 64];

    const int tid = threadIdx.x;
    const int lane = tid & 63, wave = tid >> 6;   // wnI = wave (WM=1, WN=4)
    const int m0 = blockIdx.x * TM;

    const __hip_bfloat16* gp[CH];
    #pragma unroll
    for (int c = 0; c < CH; c++) {
        int gid = c * 256 + tid;
        int row = gid >> 2, col = (gid & 3) * 8;
        gp[c] = (row < TM ? A + (size_t)(m0 + row) * K
                          : W + (size_t)(row - TM) * K) + col;
    }

    f32x4 acc[4][4] = {};
    const int fr = lane & 15, fkb = (lane >> 4) * 8;

    for (int k0 = 0; k0 < K; k0 += 32) {
        __syncthreads();
        #pragma unroll
        for (int c = 0; c < CH; c++)
            gld_lds16(gp[c] + k0, &ABs[(c * 256 + wave * 64) * 8]);
        asm volatile("s_waitcnt vmcnt(0)" ::: "memory");
        __syncthreads();
        bf16x8 a[4], b[4];
        #pragma unroll
        for (int i = 0; i < 4; i++)
            a[i] = *(const bf16x8*)&ABs[(i * 16 + fr) * 32 + fkb];
        #pragma unroll
        for (int j = 0; j < 4; j++)
            b[j] = *(const bf16x8*)&ABs[(TM + wave * 64 + j * 16 + fr) * 32 + fkb];
        #pragma unroll
        for (int i = 0; i < 4; i++)
            #pragma unroll
            for (int j = 0; j < 4; j++)
                acc[i][j] = __builtin_amdgcn_mfma_f32_16x16x32_bf16(a[i], b[j], acc[i][j], 0, 0, 0);
    }

    // epilogue: per-lane partial of sum_n relu(acc + b3[n]) * w4[n]
    float p[4][4] = {};   // [i][r]
    #pragma unroll
    for (int j = 0; j < 4; j++) {
        int n = wave * 64 + j * 16 + fr;
        float bv = b3[n], wv = w4[n];
        #pragma unroll
        for (int i = 0; i < 4; i++)
            #pragma unroll
            for (int r = 0; r < 4; r++)
                p[i][r] += fmaxf(acc[i][j][r] + bv, 0.f) * wv;
    }
    #pragma unroll
    for (int mask = 1; mask < 16; mask <<= 1)
        #pragma unroll
        for (int i = 0; i < 4; i++)
            #pragma unroll
            for (int r = 0; r < 4; r++)
                p[i][r] += __shfl_xor(p[i][r], mask, 64);
    const int fq = lane >> 4;
    if (fr == 0) {
        #pragma unroll
        for (int i = 0; i < 4; i++)
            #pragma unroll
            for (int r = 0; r < 4; r++)
                red[wave * 64 + i * 16 + fq * 4 + r] = p[i][r];
    }
    __syncthreads();
    if (tid < 64) {
        float s = red[tid] + red[64 + tid] + red[128 + tid] + red[192 + tid];
        out[m0 + tid] = 1.f / (1.f + expf(-(s + b4[0])));
    }
}

extern "C" void kernel_launch(void* const* d_in, const int* in_sizes, int n_in,
                              void* d_out, int out_size, void* d_ws, size_t ws_size,
                              hipStream_t stream) {
    const float* dense_x = (const float*)d_in[0];
    const int* sidx      = (const int*)d_in[1];
    const float* emb     = (const float*)d_in[2];
    const float* bw0 = (const float*)d_in[3];  const float* bb0 = (const float*)d_in[4];
    const float* bw1 = (const float*)d_in[5];  const float* bb1 = (const float*)d_in[6];
    const float* bw2 = (const float*)d_in[7];  const float* bb2 = (const float*)d_in[8];
    const float* tw0 = (const float*)d_in[9];  const float* tb0 = (const float*)d_in[10];
    const float* tw1 = (const float*)d_in[11]; const float* tb1 = (const float*)d_in[12];
    const float* tw2 = (const float*)d_in[13]; const float* tb2 = (const float*)d_in[14];
    const float* tw3 = (const float*)d_in[15]; const float* tb3 = (const float*)d_in[16];
    const float* tw4 = (const float*)d_in[17]; const float* tb4 = (const float*)d_in[18];
    float* out = (float*)d_out;

    char* ws = (char*)d_ws;
    size_t off = 0;
    auto alloc = [&](size_t bytes) {
        off = (off + 255) & ~(size_t)255;
        void* p = ws + off;
        off += bytes;
        return p;
    };
    __hip_bfloat16* Wb1 = (__hip_bfloat16*)alloc((size_t)256 * 512 * 2);
    __hip_bfloat16* Wb2 = (__hip_bfloat16*)alloc((size_t)128 * 256 * 2);
    __hip_bfloat16* Wt0 = (__hip_bfloat16*)alloc((size_t)1024 * 512 * 2);
    __hip_bfloat16* Wt1 = (__hip_bfloat16*)alloc((size_t)1024 * 1024 * 2);
    __hip_bfloat16* Wt2 = (__hip_bfloat16*)alloc((size_t)512 * 1024 * 2);
    __hip_bfloat16* Wt3 = (__hip_bfloat16*)alloc((size_t)256 * 512 * 2);
    __hip_bfloat16* bufA = (__hip_bfloat16*)alloc((size_t)B_SZ * 512 * 2);
    __hip_bfloat16* bufB = (__hip_bfloat16*)alloc((size_t)B_SZ * 256 * 2);
    __hip_bfloat16* Tbuf = (__hip_bfloat16*)alloc((size_t)B_SZ * TROW * 2);
    __hip_bfloat16* zbuf = (__hip_bfloat16*)alloc((size_t)B_SZ * 512 * 2);
    __hip_bfloat16* h0   = (__hip_bfloat16*)alloc((size_t)B_SZ * 1024 * 2);
    __hip_bfloat16* h1   = (__hip_bfloat16*)alloc((size_t)B_SZ * 1024 * 2);
    __hip_bfloat16* h2   = (__hip_bfloat16*)alloc((size_t)B_SZ * 512 * 2);

    CvtJobs J;
    auto setJob = [&](int i, const float* in, __hip_bfloat16* o, int N, int K, int Kp) {
        J.j[i] = {in, o, N, K, Kp};
    };
    setJob(0, bw1, Wb1, 256, 512, 512);
    setJob(1, bw2, Wb2, 128, 256, 256);
    setJob(2, tw0, Wt0, 1024, 479, 512);
    setJob(3, tw1, Wt1, 1024, 1024, 1024);
    setJob(4, tw2, Wt2, 512, 1024, 1024);
    setJob(5, tw3, Wt3, 256, 512, 512);
    J.start[0] = 0;
    for (int i = 0; i < 6; i++) J.start[i + 1] = J.start[i] + J.j[i].N * J.j[i].Kp;
    const int cvtB = (J.start[6] / 8 + 255) / 256;
    const int EMB_T = B_SZ / 4;   // blocks per table

    // L1: weight cvt || bot0 || emb(tables 0..8)
    k_pre_emb<<<cvtB + B_SZ / 4 + 9 * EMB_T, 256, 0, stream>>>(
        J, cvtB, dense_x, bw0, bb0, bufA, 0, sidx, emb, Tbuf);

    // L2: bot1 (256 tiles, 128x64) || emb(tables 9..16)
    k_gemm_emb<128, 64><<<256 + 8 * EMB_T, 256, 0, stream>>>(
        bufA, Wb1, bb1, bufB, 256 / 64, 512, 256, 256, 9, sidx, emb, Tbuf);

    // L3: bot2 (256 tiles, 64x64) -> Tbuf row 0 || emb(tables 17..25)
    k_gemm_emb<64, 64><<<256 + 9 * EMB_T, 256, 0, stream>>>(
        bufB, Wb2, bb2, Tbuf, 128 / 64, 256, TROW, 256, 17, sidx, emb, Tbuf);

    // L4: interaction -> z (B x 512, padded)
    k_int<<<B_SZ / 4, 256, 0, stream>>>(Tbuf, zbuf);

    // L5-L7: top MLP, full-width, XCD-swizzled, BK=64 + LDS XOR swizzle
    gemm_k<128,128, 2, 2><<<(B_SZ / 128) * (1024 / 128), 256, 0, stream>>>(zbuf, Wt0, tb0, h0, 1024 / 128, 512, 1024);
    gemm_k<128,128, 2, 2><<<(B_SZ / 128) * (1024 / 128), 256, 0, stream>>>(h0, Wt1, tb1, h1, 1024 / 128, 1024, 1024);
    gemm_k<128,128, 2, 2><<<(B_SZ / 128) * ( 512 / 128), 256, 0, stream>>>(h1, Wt2, tb2, h2, 512 / 128, 1024, 512);

    // L8: fused top3 + final dot + sigmoid (128 blocks, TM=64)
    k_top3_fin<<<B_SZ / 64, 256, 0, stream>>>(h2, Wt3, tb3, tw4, tb4, out);
}

// Round 13
// 287.272 us; speedup vs baseline: 1.0582x; 1.0373x over previous
//
#include <hip/hip_runtime.h>
#include <hip/hip_bf16.h>
#include <cstdint>

typedef __attribute__((ext_vector_type(8))) short bf16x8;
typedef __attribute__((ext_vector_type(4))) short bf16x4;
typedef __attribute__((ext_vector_type(4))) float f32x4;

#define B_SZ 8192
#define TROW 3456   // 27*128, per-sample stride of T buffer (bf16 elems)

__device__ __forceinline__ void gld_lds16(const void* g, void* l) {
    __builtin_amdgcn_global_load_lds(
        (const __attribute__((address_space(1))) unsigned int*)g,
        (__attribute__((address_space(3))) unsigned int*)l, 16, 0, 0);
}

__device__ __forceinline__ short f2bf_bits(float v) {
    return __builtin_bit_cast(short, __float2bfloat16(v));
}

// ---------------- weight cvt (8 elems/thread) ----------------
struct CvtJob { const float* in; __hip_bfloat16* out; int N, K, Kp; };
struct CvtJobs { CvtJob j[6]; int start[7]; };   // starts in ELEMENTS (all sizes %8==0)

__device__ __forceinline__ void cvt_dev8(int lb, int tid, const CvtJobs& J) {
    int chunk = lb * 256 + tid;
    int e = chunk * 8;
    if (e >= J.start[6]) return;
    int k = 0;
    #pragma unroll
    for (int i = 1; i < 6; i++) if (e >= J.start[i]) k = i;
    const CvtJob& job = J.j[k];
    int local = e - J.start[k];
    float v[8];
    if (job.K == job.Kp) {
        const float4* p = (const float4*)(job.in + local);
        float4 a = p[0], b = p[1];
        v[0]=a.x; v[1]=a.y; v[2]=a.z; v[3]=a.w; v[4]=b.x; v[5]=b.y; v[6]=b.z; v[7]=b.w;
    } else {
        int n = local / job.Kp, kk = local - n * job.Kp;
        #pragma unroll
        for (int i = 0; i < 8; i++)
            v[i] = (kk + i < job.K) ? job.in[(size_t)n * job.K + kk + i] : 0.f;
    }
    bf16x8 o;
    #pragma unroll
    for (int i = 0; i < 8; i++)
        o[i] = f2bf_bits(v[i]);
    *(bf16x8*)(job.out + local) = o;
}

// ---------------- bot0 fp32 (K=13) ----------------
__device__ __forceinline__ void bot0_dev(int lb, int tid, const float* __restrict__ x,
    const float* __restrict__ w, const float* __restrict__ bias,
    __hip_bfloat16* __restrict__ o, float* xs) {
    int m0 = lb * 4;
    if (tid < 52) xs[tid] = x[(size_t)m0 * 13 + tid];
    __syncthreads();
    for (int c = tid; c < 512; c += 256) {
        const float* wr = w + (size_t)c * 13;
        float bv = bias[c];
        #pragma unroll
        for (int r = 0; r < 4; r++) {
            float s = bv;
            #pragma unroll
            for (int k = 0; k < 13; k++) s += xs[r * 13 + k] * wr[k];
            o[(size_t)(m0 + r) * 512 + c] = __float2bfloat16(fmaxf(s, 0.f));
        }
    }
}

// ---------------- embedding gather-sum (16B/lane, table slice from t0) ----------------
__device__ __forceinline__ void emb_dev(int lb, int tid, int t0,
    const int* __restrict__ idx, const float* __restrict__ tab,
    __hip_bfloat16* __restrict__ T) {
    int lane = tid & 63, wv = tid >> 6;
    int p = lb * 4 + wv;
    int t = t0 + (p >> 13);
    int b = p & 8191;
    const int* ip = idx + (size_t)t * 81920 + b * 10;
    const float* tb = tab + (size_t)t * 100000 * 128;
    int half = lane >> 5, l32 = lane & 31;
    float4 s = {0.f, 0.f, 0.f, 0.f};
    #pragma unroll
    for (int j = 0; j < 10; j += 2) {
        int r = ip[j + half];
        float4 v = ((const float4*)(tb + (size_t)r * 128))[l32];
        s.x += v.x; s.y += v.y; s.z += v.z; s.w += v.w;
    }
    s.x += __shfl_xor(s.x, 32, 64);
    s.y += __shfl_xor(s.y, 32, 64);
    s.z += __shfl_xor(s.z, 32, 64);
    s.w += __shfl_xor(s.w, 32, 64);
    if (half == 0) {
        bf16x4 o;
        o[0] = f2bf_bits(s.x); o[1] = f2bf_bits(s.y);
        o[2] = f2bf_bits(s.z); o[3] = f2bf_bits(s.w);
        ((bf16x4*)(T + (size_t)b * TROW + (1 + t) * 128))[l32] = o;
    }
}

// ---------------- GEMM device core: BK=64, XOR-swizzled LDS (R10, proven) ----------------
template<int TM, int TN, int WM, int WN>
__device__ __forceinline__ void gemm_dev(int tileId, int nTiles, int nbx, int tid,
    const __hip_bfloat16* __restrict__ A, const __hip_bfloat16* __restrict__ W,
    const float* __restrict__ bias, __hip_bfloat16* __restrict__ C,
    int K, int ldc, __hip_bfloat16* ABs) {
    constexpr int BK = 64;
    constexpr int ROWS = TM + TN;
    constexpr int CH = ROWS * BK / 2048;
    constexpr int MI = TM / WM / 16;
    constexpr int NI = TN / WN / 16;

    int swz = tileId;
    if ((nTiles & 7) == 0) {
        int q = nTiles >> 3;
        swz = (tileId & 7) * q + (tileId >> 3);
    }
    const int by = swz / nbx, bx = swz - by * nbx;
    const int m0 = by * TM, n0 = bx * TN;

    const int lane = tid & 63, wave = tid >> 6;
    const int wmI = wave / WN, wnI = wave % WN;

    const __hip_bfloat16* gp[CH];
    #pragma unroll
    for (int c = 0; c < CH; c++) {
        int gid = c * 256 + tid;
        int row = gid >> 3;
        int cs = ((gid & 7) ^ (row & 7)) * 8;
        gp[c] = (row < TM ? A + (size_t)(m0 + row) * K
                          : W + (size_t)(n0 + row - TM) * K) + cs;
    }

    f32x4 acc[MI][NI] = {};
    const int fr = lane & 15, hi = lane >> 4;

    for (int k0 = 0; k0 < K; k0 += BK) {
        __syncthreads();
        #pragma unroll
        for (int c = 0; c < CH; c++)
            gld_lds16(gp[c] + k0, &ABs[(c * 256 + wave * 64) * 8]);
        asm volatile("s_waitcnt vmcnt(0)" ::: "memory");
        __syncthreads();
        #pragma unroll
        for (int ks = 0; ks < 2; ks++) {
            bf16x8 a[MI], b[NI];
            #pragma unroll
            for (int i = 0; i < MI; i++) {
                int row = wmI * (TM / WM) + i * 16 + fr;
                a[i] = *(const bf16x8*)&ABs[row * BK + (((ks * 4 + hi) ^ (row & 7)) * 8)];
            }
            #pragma unroll
            for (int j = 0; j < NI; j++) {
                int row = TM + wnI * (TN / WN) + j * 16 + fr;
                b[j] = *(const bf16x8*)&ABs[row * BK + (((ks * 4 + hi) ^ (row & 7)) * 8)];
            }
            #pragma unroll
            for (int i = 0; i < MI; i++)
                #pragma unroll
                for (int j = 0; j < NI; j++)
                    acc[i][j] = __builtin_amdgcn_mfma_f32_16x16x32_bf16(a[i], b[j], acc[i][j], 0, 0, 0);
        }
    }

    const int fq = hi;
    #pragma unroll
    for (int i = 0; i < MI; i++) {
        #pragma unroll
        for (int j = 0; j < NI; j++) {
            int n = n0 + wnI * (TN / WN) + j * 16 + fr;
            float bv = bias[n];
            #pragma unroll
            for (int r = 0; r < 4; r++) {
                int m = m0 + wmI * (TM / WM) + i * 16 + fq * 4 + r;
                C[(size_t)m * ldc + n] = __float2bfloat16(fmaxf(acc[i][j][r] + bv, 0.f));
            }
        }
    }
}

template<int TM, int TN, int WM, int WN>
__global__ __launch_bounds__(256) void gemm_k(const __hip_bfloat16* A, const __hip_bfloat16* W,
                                              const float* bias, __hip_bfloat16* C,
                                              int nbx, int K, int ldc) {
    __shared__ __align__(16) __hip_bfloat16 ABs[(TM + TN) * 64];
    gemm_dev<TM, TN, WM, WN>(blockIdx.x, gridDim.x, nbx, threadIdx.x, A, W, bias, C, K, ldc, ABs);
}

// ---------------- pipelined GEMM: BM=256, BN=128, BK=64, 512 thr, 3-buffer counted-vmcnt ----------------
// Iter t: compute K-tile t from buf[t%3]; stage tile t+2 into buf[(t+2)%3] (freed at end of
// iter t-1); iter-end vmcnt(6) retires tile t+1's 6 per-thread loads; raw s_barrier
// collectivizes per-wave guarantees. vmcnt(0) only in the 2-iteration tail.
template<int KTILES>
__global__ __launch_bounds__(512) void gemm_pipe(const __hip_bfloat16* __restrict__ A,
                                                 const __hip_bfloat16* __restrict__ W,
                                                 const float* __restrict__ bias,
                                                 __hip_bfloat16* __restrict__ C,
                                                 int nbx, int ldc) {
    constexpr int K = KTILES * 64;
    __shared__ __align__(16) __hip_bfloat16 ABs[3 * 384 * 64];   // 144 KB
    const int tid = threadIdx.x;
    const int lane = tid & 63, wave = tid >> 6;
    const int wm = wave >> 2, wn = wave & 3;        // 2M x 4N wave grid

    int swz = blockIdx.x;                            // grid %8 == 0
    { int q = (int)gridDim.x >> 3; swz = (swz & 7) * q + (swz >> 3); }
    const int by = swz / nbx, bx = swz - by * nbx;
    const int m0 = by * 256, n0 = bx * 128;

    // staging: 6 rounds x 512 threads x 16B = 48KB = one K-tile (A 256 rows + W 128 rows)
    const __hip_bfloat16* gp[6];
    #pragma unroll
    for (int r = 0; r < 6; r++) {
        int gid = r * 512 + tid;
        int row = gid >> 3;                          // 8 x 16B chunks per 64-elem row
        int cs = ((gid & 7) ^ (row & 7)) * 8;        // pre-swizzled source column
        gp[r] = (row < 256 ? A + (size_t)(m0 + row) * K
                           : W + (size_t)(n0 + row - 256) * K) + cs;
    }
    auto stage3 = [&](int s, int t, int r0) {
        __hip_bfloat16* dst = &ABs[s * 384 * 64];
        #pragma unroll
        for (int r = 0; r < 3; r++)
            gld_lds16(gp[r0 + r] + t * 64, &dst[((r0 + r) * 512 + wave * 64) * 8]);
    };

    f32x4 acc[8][2] = {};
    const int fr = lane & 15, hi = lane >> 4;

    // prologue: stage tiles 0 and 1
    stage3(0, 0, 0); stage3(0, 0, 3);
    stage3(1, 1, 0); stage3(1, 1, 3);
    asm volatile("s_waitcnt vmcnt(6)" ::: "memory");   // tile 0 landed
    __builtin_amdgcn_s_barrier();

    for (int t = 0; t < KTILES; ++t) {
        const __hip_bfloat16* buf = &ABs[(t % 3) * 384 * 64];
        const bool pf = (t + 2) < KTILES;
        const int s2 = (t + 2) % 3;

        // phase A: issue half the prefetch, compute kslab 0
        if (pf) stage3(s2, t + 2, 0);
        {
            bf16x8 a[8], b[2];
            #pragma unroll
            for (int i = 0; i < 8; i++) {
                int row = wm * 128 + i * 16 + fr;
                a[i] = *(const bf16x8*)&buf[row * 64 + ((hi ^ (row & 7)) * 8)];
            }
            #pragma unroll
            for (int j = 0; j < 2; j++) {
                int row = 256 + wn * 32 + j * 16 + fr;
                b[j] = *(const bf16x8*)&buf[row * 64 + ((hi ^ (row & 7)) * 8)];
            }
            __builtin_amdgcn_s_setprio(1);
            #pragma unroll
            for (int i = 0; i < 8; i++)
                #pragma unroll
                for (int j = 0; j < 2; j++)
                    acc[i][j] = __builtin_amdgcn_mfma_f32_16x16x32_bf16(a[i], b[j], acc[i][j], 0, 0, 0);
            __builtin_amdgcn_s_setprio(0);
        }
        __builtin_amdgcn_s_barrier();   // phase split (scheduling aid)

        // phase B: issue rest of prefetch, compute kslab 1
        if (pf) stage3(s2, t + 2, 3);
        {
            bf16x8 a[8], b[2];
            #pragma unroll
            for (int i = 0; i < 8; i++) {
                int row = wm * 128 + i * 16 + fr;
                a[i] = *(const bf16x8*)&buf[row * 64 + (((4 + hi) ^ (row & 7)) * 8)];
            }
            #pragma unroll
            for (int j = 0; j < 2; j++) {
                int row = 256 + wn * 32 + j * 16 + fr;
                b[j] = *(const bf16x8*)&buf[row * 64 + (((4 + hi) ^ (row & 7)) * 8)];
            }
            __builtin_amdgcn_s_setprio(1);
            #pragma unroll
            for (int i = 0; i < 8; i++)
                #pragma unroll
                for (int j = 0; j < 2; j++)
                    acc[i][j] = __builtin_amdgcn_mfma_f32_16x16x32_bf16(a[i], b[j], acc[i][j], 0, 0, 0);
            __builtin_amdgcn_s_setprio(0);
        }
        // iteration end: tile t+1 must be landed before next iter reads it
        if (pf) asm volatile("s_waitcnt vmcnt(6)" ::: "memory");
        else    asm volatile("s_waitcnt vmcnt(0)" ::: "memory");
        __builtin_amdgcn_s_barrier();
    }

    // epilogue
    #pragma unroll
    for (int i = 0; i < 8; i++) {
        #pragma unroll
        for (int j = 0; j < 2; j++) {
            int n = n0 + wn * 32 + j * 16 + fr;
            float bv = bias[n];
            #pragma unroll
            for (int r = 0; r < 4; r++) {
                int m = m0 + wm * 128 + i * 16 + hi * 4 + r;
                C[(size_t)m * ldc + n] = __float2bfloat16(fmaxf(acc[i][j][r] + bv, 0.f));
            }
        }
    }
}

// L1: cvt || bot0 || emb(tables t0..)
__global__ __launch_bounds__(256) void k_pre_emb(CvtJobs J, int cvtB,
    const float* dx, const float* w0, const float* b0, __hip_bfloat16* bufA,
    int t0, const int* sidx, const float* tab, __hip_bfloat16* T) {
    __shared__ float xs[64];
    int blk = blockIdx.x, tid = threadIdx.x;
    if (blk < cvtB) { cvt_dev8(blk, tid, J); return; }
    blk -= cvtB;
    if (blk < B_SZ / 4) { bot0_dev(blk, tid, dx, w0, b0, bufA, xs); return; }
    emb_dev(blk - B_SZ / 4, tid, t0, sidx, tab, T);
}

// gemm || emb(tables t0..)
template<int TM, int TN>
__global__ __launch_bounds__(256) void k_gemm_emb(const __hip_bfloat16* A, const __hip_bfloat16* W,
    const float* bias, __hip_bfloat16* C, int nbx, int K, int ldc, int gB,
    int t0, const int* sidx, const float* tab, __hip_bfloat16* T) {
    __shared__ __align__(16) __hip_bfloat16 ABs[(TM + TN) * 64];
    if (blockIdx.x < gB)
        gemm_dev<TM, TN, 2, 2>(blockIdx.x, gB, nbx, threadIdx.x, A, W, bias, C, K, ldc, ABs);
    else
        emb_dev(blockIdx.x - gB, threadIdx.x, t0, sidx, tab, T);
}

// ---------------- interaction (LDS-free): 4 samples/block ----------------
__global__ __launch_bounds__(256) void k_int(const __hip_bfloat16* __restrict__ T,
                                             __hip_bfloat16* __restrict__ z) {
    int lane = threadIdx.x & 63, wave = threadIdx.x >> 6;
    int b = blockIdx.x * 4 + wave;
    const __hip_bfloat16* Tb = T + (size_t)b * TROW;

    const int fr = lane & 15, fkb = (lane >> 4) * 8;
    bf16x8 fr2[2][4];
    #pragma unroll
    for (int mi = 0; mi < 2; mi++)
        #pragma unroll
        for (int kt = 0; kt < 4; kt++)
            fr2[mi][kt] = *(const bf16x8*)&Tb[(mi * 16 + fr) * 128 + kt * 32 + fkb];

    f32x4 acc[2][2] = {};
    #pragma unroll
    for (int kt = 0; kt < 4; kt++)
        #pragma unroll
        for (int mi = 0; mi < 2; mi++)
            #pragma unroll
            for (int ni = 0; ni < 2; ni++)
                acc[mi][ni] = __builtin_amdgcn_mfma_f32_16x16x32_bf16(fr2[mi][kt], fr2[ni][kt], acc[mi][ni], 0, 0, 0);

    __hip_bfloat16* zb = z + (size_t)b * 512;
    ((unsigned*)zb)[lane] = ((const unsigned*)Tb)[lane];       // copy x row (128 bf16)
    if (lane < 33) zb[479 + lane] = __float2bfloat16(0.f);     // pad cols 479..511
    const int fq = lane >> 4;
    #pragma unroll
    for (int mi = 0; mi < 2; mi++)
        #pragma unroll
        for (int ni = 0; ni < 2; ni++)
            #pragma unroll
            for (int r = 0; r < 4; r++) {
                int m = mi * 16 + fq * 4 + r;
                int n = ni * 16 + fr;
                if (m < 27 && n < 27 && m < n) {
                    int p = m * 26 - (m * (m - 1)) / 2 + (n - m - 1);
                    zb[128 + p] = __float2bfloat16(acc[mi][ni][r]);
                }
            }
}

// ---------------- fused top3+final: TM=64, TN=256, K=512, BK=32 (R10, proven) ----------------
__global__ __launch_bounds__(256) void k_top3_fin(const __hip_bfloat16* __restrict__ A,
                                                  const __hip_bfloat16* __restrict__ W,
                                                  const float* __restrict__ b3,
                                                  const float* __restrict__ w4,
                                                  const float* __restrict__ b4,
                                                  float* __restrict__ out) {
    constexpr int TM = 64, TN = 256, K = 512;
    constexpr int ROWS = TM + TN;           // 320
    constexpr int CH = ROWS * 4 / 256;      // 5
    __shared__ __align__(16) __hip_bfloat16 ABs[ROWS * 32];
    __shared__ float red[4 * 64];

    const int tid = threadIdx.x;
    const int lane = tid & 63, wave = tid >> 6;
    const int m0 = blockIdx.x * TM;

    const __hip_bfloat16* gp[CH];
    #pragma unroll
    for (int c = 0; c < CH; c++) {
        int gid = c * 256 + tid;
        int row = gid >> 2, col = (gid & 3) * 8;
        gp[c] = (row < TM ? A + (size_t)(m0 + row) * K
                          : W + (size_t)(row - TM) * K) + col;
    }

    f32x4 acc[4][4] = {};
    const int fr = lane & 15, fkb = (lane >> 4) * 8;

    for (int k0 = 0; k0 < K; k0 += 32) {
        __syncthreads();
        #pragma unroll
        for (int c = 0; c < CH; c++)
            gld_lds16(gp[c] + k0, &ABs[(c * 256 + wave * 64) * 8]);
        asm volatile("s_waitcnt vmcnt(0)" ::: "memory");
        __syncthreads();
        bf16x8 a[4], b[4];
        #pragma unroll
        for (int i = 0; i < 4; i++)
            a[i] = *(const bf16x8*)&ABs[(i * 16 + fr) * 32 + fkb];
        #pragma unroll
        for (int j = 0; j < 4; j++)
            b[j] = *(const bf16x8*)&ABs[(TM + wave * 64 + j * 16 + fr) * 32 + fkb];
        #pragma unroll
        for (int i = 0; i < 4; i++)
            #pragma unroll
            for (int j = 0; j < 4; j++)
                acc[i][j] = __builtin_amdgcn_mfma_f32_16x16x32_bf16(a[i], b[j], acc[i][j], 0, 0, 0);
    }

    float p[4][4] = {};
    #pragma unroll
    for (int j = 0; j < 4; j++) {
        int n = wave * 64 + j * 16 + fr;
        float bv = b3[n], wv = w4[n];
        #pragma unroll
        for (int i = 0; i < 4; i++)
            #pragma unroll
            for (int r = 0; r < 4; r++)
                p[i][r] += fmaxf(acc[i][j][r] + bv, 0.f) * wv;
    }
    #pragma unroll
    for (int mask = 1; mask < 16; mask <<= 1)
        #pragma unroll
        for (int i = 0; i < 4; i++)
            #pragma unroll
            for (int r = 0; r < 4; r++)
                p[i][r] += __shfl_xor(p[i][r], mask, 64);
    const int fq = lane >> 4;
    if (fr == 0) {
        #pragma unroll
        for (int i = 0; i < 4; i++)
            #pragma unroll
            for (int r = 0; r < 4; r++)
                red[wave * 64 + i * 16 + fq * 4 + r] = p[i][r];
    }
    __syncthreads();
    if (tid < 64) {
        float s = red[tid] + red[64 + tid] + red[128 + tid] + red[192 + tid];
        out[m0 + tid] = 1.f / (1.f + expf(-(s + b4[0])));
    }
}

extern "C" void kernel_launch(void* const* d_in, const int* in_sizes, int n_in,
                              void* d_out, int out_size, void* d_ws, size_t ws_size,
                              hipStream_t stream) {
    const float* dense_x = (const float*)d_in[0];
    const int* sidx      = (const int*)d_in[1];
    const float* emb     = (const float*)d_in[2];
    const float* bw0 = (const float*)d_in[3];  const float* bb0 = (const float*)d_in[4];
    const float* bw1 = (const float*)d_in[5];  const float* bb1 = (const float*)d_in[6];
    const float* bw2 = (const float*)d_in[7];  const float* bb2 = (const float*)d_in[8];
    const float* tw0 = (const float*)d_in[9];  const float* tb0 = (const float*)d_in[10];
    const float* tw1 = (const float*)d_in[11]; const float* tb1 = (const float*)d_in[12];
    const float* tw2 = (const float*)d_in[13]; const float* tb2 = (const float*)d_in[14];
    const float* tw3 = (const float*)d_in[15]; const float* tb3 = (const float*)d_in[16];
    const float* tw4 = (const float*)d_in[17]; const float* tb4 = (const float*)d_in[18];
    float* out = (float*)d_out;

    char* ws = (char*)d_ws;
    size_t off = 0;
    auto alloc = [&](size_t bytes) {
        off = (off + 255) & ~(size_t)255;
        void* p = ws + off;
        off += bytes;
        return p;
    };
    __hip_bfloat16* Wb1 = (__hip_bfloat16*)alloc((size_t)256 * 512 * 2);
    __hip_bfloat16* Wb2 = (__hip_bfloat16*)alloc((size_t)128 * 256 * 2);
    __hip_bfloat16* Wt0 = (__hip_bfloat16*)alloc((size_t)1024 * 512 * 2);
    __hip_bfloat16* Wt1 = (__hip_bfloat16*)alloc((size_t)1024 * 1024 * 2);
    __hip_bfloat16* Wt2 = (__hip_bfloat16*)alloc((size_t)512 * 1024 * 2);
    __hip_bfloat16* Wt3 = (__hip_bfloat16*)alloc((size_t)256 * 512 * 2);
    __hip_bfloat16* bufA = (__hip_bfloat16*)alloc((size_t)B_SZ * 512 * 2);
    __hip_bfloat16* bufB = (__hip_bfloat16*)alloc((size_t)B_SZ * 256 * 2);
    __hip_bfloat16* Tbuf = (__hip_bfloat16*)alloc((size_t)B_SZ * TROW * 2);
    __hip_bfloat16* zbuf = (__hip_bfloat16*)alloc((size_t)B_SZ * 512 * 2);
    __hip_bfloat16* h0   = (__hip_bfloat16*)alloc((size_t)B_SZ * 1024 * 2);
    __hip_bfloat16* h1   = (__hip_bfloat16*)alloc((size_t)B_SZ * 1024 * 2);
    __hip_bfloat16* h2   = (__hip_bfloat16*)alloc((size_t)B_SZ * 512 * 2);

    CvtJobs J;
    auto setJob = [&](int i, const float* in, __hip_bfloat16* o, int N, int K, int Kp) {
        J.j[i] = {in, o, N, K, Kp};
    };
    setJob(0, bw1, Wb1, 256, 512, 512);
    setJob(1, bw2, Wb2, 128, 256, 256);
    setJob(2, tw0, Wt0, 1024, 479, 512);
    setJob(3, tw1, Wt1, 1024, 1024, 1024);
    setJob(4, tw2, Wt2, 512, 1024, 1024);
    setJob(5, tw3, Wt3, 256, 512, 512);
    J.start[0] = 0;
    for (int i = 0; i < 6; i++) J.start[i + 1] = J.start[i] + J.j[i].N * J.j[i].Kp;
    const int cvtB = (J.start[6] / 8 + 255) / 256;
    const int EMB_T = B_SZ / 4;   // blocks per table

    // L1: weight cvt || bot0 || emb(tables 0..8)
    k_pre_emb<<<cvtB + B_SZ / 4 + 9 * EMB_T, 256, 0, stream>>>(
        J, cvtB, dense_x, bw0, bb0, bufA, 0, sidx, emb, Tbuf);

    // L2: bot1 (256 tiles, 128x64) || emb(tables 9..16)
    k_gemm_emb<128, 64><<<256 + 8 * EMB_T, 256, 0, stream>>>(
        bufA, Wb1, bb1, bufB, 256 / 64, 512, 256, 256, 9, sidx, emb, Tbuf);

    // L3: bot2 (256 tiles, 64x64) -> Tbuf row 0 || emb(tables 17..25)
    k_gemm_emb<64, 64><<<256 + 9 * EMB_T, 256, 0, stream>>>(
        bufB, Wb2, bb2, Tbuf, 128 / 64, 256, TROW, 256, 17, sidx, emb, Tbuf);

    // L4: interaction -> z (B x 512, padded)
    k_int<<<B_SZ / 4, 256, 0, stream>>>(Tbuf, zbuf);

    // L5-L6: top0/top1 via 256x128 3-buffer counted-vmcnt pipeline (256 blocks = 1/CU)
    gemm_pipe< 8><<<(B_SZ / 256) * (1024 / 128), 512, 0, stream>>>(zbuf, Wt0, tb0, h0, 1024 / 128, 1024);
    gemm_pipe<16><<<(B_SZ / 256) * (1024 / 128), 512, 0, stream>>>(h0, Wt1, tb1, h1, 1024 / 128, 1024);

    // L7: top2 via proven 128x128 BK=64 kernel
    gemm_k<128,128, 2, 2><<<(B_SZ / 128) * ( 512 / 128), 256, 0, stream>>>(h1, Wt2, tb2, h2, 512 / 128, 1024, 512);

    // L8: fused top3 + final dot + sigmoid (128 blocks, TM=64)
    k_top3_fin<<<B_SZ / 64, 256, 0, stream>>>(h2, Wt3, tb3, tw4, tb4, out);
}

// Round 14
// 274.829 us; speedup vs baseline: 1.1061x; 1.0453x over previous
//
#include <hip/hip_runtime.h>
#include <hip/hip_bf16.h>
#include <cstdint>

typedef __attribute__((ext_vector_type(8))) short bf16x8;
typedef __attribute__((ext_vector_type(4))) short bf16x4;
typedef __attribute__((ext_vector_type(4))) float f32x4;

#define B_SZ 8192
#define TROW 3456   // 27*128, per-sample stride of T buffer (bf16 elems)

__device__ __forceinline__ void gld_lds16(const void* g, void* l) {
    __builtin_amdgcn_global_load_lds(
        (const __attribute__((address_space(1))) unsigned int*)g,
        (__attribute__((address_space(3))) unsigned int*)l, 16, 0, 0);
}

__device__ __forceinline__ short f2bf_bits(float v) {
    return __builtin_bit_cast(short, __float2bfloat16(v));
}

template<int N> __device__ __forceinline__ void waitcnt_vm() {
    if constexpr (N == 0) asm volatile("s_waitcnt vmcnt(0)" ::: "memory");
    else if constexpr (N == 4) asm volatile("s_waitcnt vmcnt(4)" ::: "memory");
    else if constexpr (N == 6) asm volatile("s_waitcnt vmcnt(6)" ::: "memory");
}

// ---------------- weight cvt (8 elems/thread) ----------------
struct CvtJob { const float* in; __hip_bfloat16* out; int N, K, Kp; };
struct CvtJobs { CvtJob j[6]; int start[7]; };   // starts in ELEMENTS (all sizes %8==0)

__device__ __forceinline__ void cvt_dev8(int lb, int tid, const CvtJobs& J) {
    int chunk = lb * 256 + tid;
    int e = chunk * 8;
    if (e >= J.start[6]) return;
    int k = 0;
    #pragma unroll
    for (int i = 1; i < 6; i++) if (e >= J.start[i]) k = i;
    const CvtJob& job = J.j[k];
    int local = e - J.start[k];
    float v[8];
    if (job.K == job.Kp) {
        const float4* p = (const float4*)(job.in + local);
        float4 a = p[0], b = p[1];
        v[0]=a.x; v[1]=a.y; v[2]=a.z; v[3]=a.w; v[4]=b.x; v[5]=b.y; v[6]=b.z; v[7]=b.w;
    } else {
        int n = local / job.Kp, kk = local - n * job.Kp;
        #pragma unroll
        for (int i = 0; i < 8; i++)
            v[i] = (kk + i < job.K) ? job.in[(size_t)n * job.K + kk + i] : 0.f;
    }
    bf16x8 o;
    #pragma unroll
    for (int i = 0; i < 8; i++)
        o[i] = f2bf_bits(v[i]);
    *(bf16x8*)(job.out + local) = o;
}

// ---------------- bot0 fp32 (K=13) ----------------
__device__ __forceinline__ void bot0_dev(int lb, int tid, const float* __restrict__ x,
    const float* __restrict__ w, const float* __restrict__ bias,
    __hip_bfloat16* __restrict__ o, float* xs) {
    int m0 = lb * 4;
    if (tid < 52) xs[tid] = x[(size_t)m0 * 13 + tid];
    __syncthreads();
    for (int c = tid; c < 512; c += 256) {
        const float* wr = w + (size_t)c * 13;
        float bv = bias[c];
        #pragma unroll
        for (int r = 0; r < 4; r++) {
            float s = bv;
            #pragma unroll
            for (int k = 0; k < 13; k++) s += xs[r * 13 + k] * wr[k];
            o[(size_t)(m0 + r) * 512 + c] = __float2bfloat16(fmaxf(s, 0.f));
        }
    }
}

// ---------------- embedding gather-sum (16B/lane, table slice from t0) ----------------
__device__ __forceinline__ void emb_dev(int lb, int tid, int t0,
    const int* __restrict__ idx, const float* __restrict__ tab,
    __hip_bfloat16* __restrict__ T) {
    int lane = tid & 63, wv = tid >> 6;
    int p = lb * 4 + wv;
    int t = t0 + (p >> 13);
    int b = p & 8191;
    const int* ip = idx + (size_t)t * 81920 + b * 10;
    const float* tb = tab + (size_t)t * 100000 * 128;
    int half = lane >> 5, l32 = lane & 31;
    float4 s = {0.f, 0.f, 0.f, 0.f};
    #pragma unroll
    for (int j = 0; j < 10; j += 2) {
        int r = ip[j + half];
        float4 v = ((const float4*)(tb + (size_t)r * 128))[l32];
        s.x += v.x; s.y += v.y; s.z += v.z; s.w += v.w;
    }
    s.x += __shfl_xor(s.x, 32, 64);
    s.y += __shfl_xor(s.y, 32, 64);
    s.z += __shfl_xor(s.z, 32, 64);
    s.w += __shfl_xor(s.w, 32, 64);
    if (half == 0) {
        bf16x4 o;
        o[0] = f2bf_bits(s.x); o[1] = f2bf_bits(s.y);
        o[2] = f2bf_bits(s.z); o[3] = f2bf_bits(s.w);
        ((bf16x4*)(T + (size_t)b * TROW + (1 + t) * 128))[l32] = o;
    }
}

// ---------------- GEMM device core: BK=64, XOR-swizzled LDS (R10, proven) ----------------
template<int TM, int TN, int WM, int WN>
__device__ __forceinline__ void gemm_dev(int tileId, int nTiles, int nbx, int tid,
    const __hip_bfloat16* __restrict__ A, const __hip_bfloat16* __restrict__ W,
    const float* __restrict__ bias, __hip_bfloat16* __restrict__ C,
    int K, int ldc, __hip_bfloat16* ABs) {
    constexpr int BK = 64;
    constexpr int ROWS = TM + TN;
    constexpr int CH = ROWS * BK / 2048;
    constexpr int MI = TM / WM / 16;
    constexpr int NI = TN / WN / 16;

    int swz = tileId;
    if ((nTiles & 7) == 0) {
        int q = nTiles >> 3;
        swz = (tileId & 7) * q + (tileId >> 3);
    }
    const int by = swz / nbx, bx = swz - by * nbx;
    const int m0 = by * TM, n0 = bx * TN;

    const int lane = tid & 63, wave = tid >> 6;
    const int wmI = wave / WN, wnI = wave % WN;

    const __hip_bfloat16* gp[CH];
    #pragma unroll
    for (int c = 0; c < CH; c++) {
        int gid = c * 256 + tid;
        int row = gid >> 3;
        int cs = ((gid & 7) ^ (row & 7)) * 8;
        gp[c] = (row < TM ? A + (size_t)(m0 + row) * K
                          : W + (size_t)(n0 + row - TM) * K) + cs;
    }

    f32x4 acc[MI][NI] = {};
    const int fr = lane & 15, hi = lane >> 4;

    for (int k0 = 0; k0 < K; k0 += BK) {
        __syncthreads();
        #pragma unroll
        for (int c = 0; c < CH; c++)
            gld_lds16(gp[c] + k0, &ABs[(c * 256 + wave * 64) * 8]);
        asm volatile("s_waitcnt vmcnt(0)" ::: "memory");
        __syncthreads();
        #pragma unroll
        for (int ks = 0; ks < 2; ks++) {
            bf16x8 a[MI], b[NI];
            #pragma unroll
            for (int i = 0; i < MI; i++) {
                int row = wmI * (TM / WM) + i * 16 + fr;
                a[i] = *(const bf16x8*)&ABs[row * BK + (((ks * 4 + hi) ^ (row & 7)) * 8)];
            }
            #pragma unroll
            for (int j = 0; j < NI; j++) {
                int row = TM + wnI * (TN / WN) + j * 16 + fr;
                b[j] = *(const bf16x8*)&ABs[row * BK + (((ks * 4 + hi) ^ (row & 7)) * 8)];
            }
            #pragma unroll
            for (int i = 0; i < MI; i++)
                #pragma unroll
                for (int j = 0; j < NI; j++)
                    acc[i][j] = __builtin_amdgcn_mfma_f32_16x16x32_bf16(a[i], b[j], acc[i][j], 0, 0, 0);
        }
    }

    const int fq = hi;
    #pragma unroll
    for (int i = 0; i < MI; i++) {
        #pragma unroll
        for (int j = 0; j < NI; j++) {
            int n = n0 + wnI * (TN / WN) + j * 16 + fr;
            float bv = bias[n];
            #pragma unroll
            for (int r = 0; r < 4; r++) {
                int m = m0 + wmI * (TM / WM) + i * 16 + fq * 4 + r;
                C[(size_t)m * ldc + n] = __float2bfloat16(fmaxf(acc[i][j][r] + bv, 0.f));
            }
        }
    }
}

template<int TM, int TN, int WM, int WN>
__global__ __launch_bounds__(256) void gemm_k(const __hip_bfloat16* A, const __hip_bfloat16* W,
                                              const float* bias, __hip_bfloat16* C,
                                              int nbx, int K, int ldc) {
    __shared__ __align__(16) __hip_bfloat16 ABs[(TM + TN) * 64];
    gemm_dev<TM, TN, WM, WN>(blockIdx.x, gridDim.x, nbx, threadIdx.x, A, W, bias, C, K, ldc, ABs);
}

// ---------------- pipelined GEMM: BM x 128, BK=64, 512 thr, 3-buffer counted-vmcnt ----------------
// Iter t: compute K-tile t from buf[t%3]; stage tile t+2 into buf[(t+2)%3] (freed at end of
// iter t-1); iter-end vmcnt(R) retires tile t+1's R per-thread loads; raw s_barrier
// collectivizes per-wave guarantees. vmcnt(0) only in the final 2 iterations.
template<int BM, int KTILES>
__global__ __launch_bounds__(512) void gemm_pipe(const __hip_bfloat16* __restrict__ A,
                                                 const __hip_bfloat16* __restrict__ W,
                                                 const float* __restrict__ bias,
                                                 __hip_bfloat16* __restrict__ C,
                                                 int nbx, int ldc) {
    constexpr int K = KTILES * 64;
    constexpr int ROWS = BM + 128;
    constexpr int R = ROWS / 64;           // staging rounds per K-tile (6 for BM=256, 4 for BM=128)
    constexpr int MI = BM / 2 / 16;        // per-wave M fragments (8 or 4)
    __shared__ __align__(16) __hip_bfloat16 ABs[3 * ROWS * 64];
    const int tid = threadIdx.x;
    const int lane = tid & 63, wave = tid >> 6;
    const int wm = wave >> 2, wn = wave & 3;        // 2M x 4N wave grid

    int swz = blockIdx.x;                            // grid %8 == 0
    { int q = (int)gridDim.x >> 3; swz = (swz & 7) * q + (swz >> 3); }
    const int by = swz / nbx, bx = swz - by * nbx;
    const int m0 = by * BM, n0 = bx * 128;

    // staging: R rounds x 512 threads x 16B per K-tile (A BM rows + W 128 rows)
    const __hip_bfloat16* gp[R];
    #pragma unroll
    for (int r = 0; r < R; r++) {
        int gid = r * 512 + tid;
        int row = gid >> 3;                          // 8 x 16B chunks per 64-elem row
        int cs = ((gid & 7) ^ (row & 7)) * 8;        // pre-swizzled source column
        gp[r] = (row < BM ? A + (size_t)(m0 + row) * K
                          : W + (size_t)(n0 + row - BM) * K) + cs;
    }
    auto stageH = [&](int s, int t, int h) {         // half-tile staging (R/2 rounds)
        __hip_bfloat16* dst = &ABs[s * ROWS * 64];
        #pragma unroll
        for (int r = h * (R / 2); r < (h + 1) * (R / 2); r++)
            gld_lds16(gp[r] + t * 64, &dst[(r * 512 + wave * 64) * 8]);
    };

    f32x4 acc[MI][2] = {};
    const int fr = lane & 15, hi = lane >> 4;

    // prologue: stage tiles 0 and 1
    stageH(0, 0, 0); stageH(0, 0, 1);
    stageH(1, 1, 0); stageH(1, 1, 1);
    waitcnt_vm<R>();                     // tile 0 landed (tile 1's R loads outstanding)
    __builtin_amdgcn_s_barrier();

    for (int t = 0; t < KTILES; ++t) {
        const __hip_bfloat16* buf = &ABs[(t % 3) * ROWS * 64];
        const bool pf = (t + 2) < KTILES;
        const int s2 = (t + 2) % 3;

        // phase A: issue half the prefetch, compute kslab 0
        if (pf) stageH(s2, t + 2, 0);
        {
            bf16x8 a[MI], b[2];
            #pragma unroll
            for (int i = 0; i < MI; i++) {
                int row = wm * (BM / 2) + i * 16 + fr;
                a[i] = *(const bf16x8*)&buf[row * 64 + ((hi ^ (row & 7)) * 8)];
            }
            #pragma unroll
            for (int j = 0; j < 2; j++) {
                int row = BM + wn * 32 + j * 16 + fr;
                b[j] = *(const bf16x8*)&buf[row * 64 + ((hi ^ (row & 7)) * 8)];
            }
            __builtin_amdgcn_s_setprio(1);
            #pragma unroll
            for (int i = 0; i < MI; i++)
                #pragma unroll
                for (int j = 0; j < 2; j++)
                    acc[i][j] = __builtin_amdgcn_mfma_f32_16x16x32_bf16(a[i], b[j], acc[i][j], 0, 0, 0);
            __builtin_amdgcn_s_setprio(0);
        }
        __builtin_amdgcn_s_barrier();   // phase split (scheduling aid)

        // phase B: issue rest of prefetch, compute kslab 1
        if (pf) stageH(s2, t + 2, 1);
        {
            bf16x8 a[MI], b[2];
            #pragma unroll
            for (int i = 0; i < MI; i++) {
                int row = wm * (BM / 2) + i * 16 + fr;
                a[i] = *(const bf16x8*)&buf[row * 64 + (((4 + hi) ^ (row & 7)) * 8)];
            }
            #pragma unroll
            for (int j = 0; j < 2; j++) {
                int row = BM + wn * 32 + j * 16 + fr;
                b[j] = *(const bf16x8*)&buf[row * 64 + (((4 + hi) ^ (row & 7)) * 8)];
            }
            __builtin_amdgcn_s_setprio(1);
            #pragma unroll
            for (int i = 0; i < MI; i++)
                #pragma unroll
                for (int j = 0; j < 2; j++)
                    acc[i][j] = __builtin_amdgcn_mfma_f32_16x16x32_bf16(a[i], b[j], acc[i][j], 0, 0, 0);
            __builtin_amdgcn_s_setprio(0);
        }
        // iteration end: tile t+1 must be landed before next iter reads it
        if (pf) waitcnt_vm<R>();
        else    waitcnt_vm<0>();
        __builtin_amdgcn_s_barrier();
    }

    // epilogue
    #pragma unroll
    for (int i = 0; i < MI; i++) {
        #pragma unroll
        for (int j = 0; j < 2; j++) {
            int n = n0 + wn * 32 + j * 16 + fr;
            float bv = bias[n];
            #pragma unroll
            for (int r = 0; r < 4; r++) {
                int m = m0 + wm * (BM / 2) + i * 16 + hi * 4 + r;
                C[(size_t)m * ldc + n] = __float2bfloat16(fmaxf(acc[i][j][r] + bv, 0.f));
            }
        }
    }
}

// L1: cvt || bot0 || emb(tables t0..)
__global__ __launch_bounds__(256) void k_pre_emb(CvtJobs J, int cvtB,
    const float* dx, const float* w0, const float* b0, __hip_bfloat16* bufA,
    int t0, const int* sidx, const float* tab, __hip_bfloat16* T) {
    __shared__ float xs[64];
    int blk = blockIdx.x, tid = threadIdx.x;
    if (blk < cvtB) { cvt_dev8(blk, tid, J); return; }
    blk -= cvtB;
    if (blk < B_SZ / 4) { bot0_dev(blk, tid, dx, w0, b0, bufA, xs); return; }
    emb_dev(blk - B_SZ / 4, tid, t0, sidx, tab, T);
}

// gemm || emb(tables t0..)
template<int TM, int TN>
__global__ __launch_bounds__(256) void k_gemm_emb(const __hip_bfloat16* A, const __hip_bfloat16* W,
    const float* bias, __hip_bfloat16* C, int nbx, int K, int ldc, int gB,
    int t0, const int* sidx, const float* tab, __hip_bfloat16* T) {
    __shared__ __align__(16) __hip_bfloat16 ABs[(TM + TN) * 64];
    if (blockIdx.x < gB)
        gemm_dev<TM, TN, 2, 2>(blockIdx.x, gB, nbx, threadIdx.x, A, W, bias, C, K, ldc, ABs);
    else
        emb_dev(blockIdx.x - gB, threadIdx.x, t0, sidx, tab, T);
}

// ---------------- interaction (LDS-free): 4 samples/block ----------------
__global__ __launch_bounds__(256) void k_int(const __hip_bfloat16* __restrict__ T,
                                             __hip_bfloat16* __restrict__ z) {
    int lane = threadIdx.x & 63, wave = threadIdx.x >> 6;
    int b = blockIdx.x * 4 + wave;
    const __hip_bfloat16* Tb = T + (size_t)b * TROW;

    const int fr = lane & 15, fkb = (lane >> 4) * 8;
    bf16x8 fr2[2][4];
    #pragma unroll
    for (int mi = 0; mi < 2; mi++)
        #pragma unroll
        for (int kt = 0; kt < 4; kt++)
            fr2[mi][kt] = *(const bf16x8*)&Tb[(mi * 16 + fr) * 128 + kt * 32 + fkb];

    f32x4 acc[2][2] = {};
    #pragma unroll
    for (int kt = 0; kt < 4; kt++)
        #pragma unroll
        for (int mi = 0; mi < 2; mi++)
            #pragma unroll
            for (int ni = 0; ni < 2; ni++)
                acc[mi][ni] = __builtin_amdgcn_mfma_f32_16x16x32_bf16(fr2[mi][kt], fr2[ni][kt], acc[mi][ni], 0, 0, 0);

    __hip_bfloat16* zb = z + (size_t)b * 512;
    ((unsigned*)zb)[lane] = ((const unsigned*)Tb)[lane];       // copy x row (128 bf16)
    if (lane < 33) zb[479 + lane] = __float2bfloat16(0.f);     // pad cols 479..511
    const int fq = lane >> 4;
    #pragma unroll
    for (int mi = 0; mi < 2; mi++)
        #pragma unroll
        for (int ni = 0; ni < 2; ni++)
            #pragma unroll
            for (int r = 0; r < 4; r++) {
                int m = mi * 16 + fq * 4 + r;
                int n = ni * 16 + fr;
                if (m < 27 && n < 27 && m < n) {
                    int p = m * 26 - (m * (m - 1)) / 2 + (n - m - 1);
                    zb[128 + p] = __float2bfloat16(acc[mi][ni][r]);
                }
            }
}

// ---------------- fused top3+final: TM=64, TN=256, K=512, BK=32 (R10, proven) ----------------
__global__ __launch_bounds__(256) void k_top3_fin(const __hip_bfloat16* __restrict__ A,
                                                  const __hip_bfloat16* __restrict__ W,
                                                  const float* __restrict__ b3,
                                                  const float* __restrict__ w4,
                                                  const float* __restrict__ b4,
                                                  float* __restrict__ out) {
    constexpr int TM = 64, TN = 256, K = 512;
    constexpr int ROWS = TM + TN;           // 320
    constexpr int CH = ROWS * 4 / 256;      // 5
    __shared__ __align__(16) __hip_bfloat16 ABs[ROWS * 32];
    __shared__ float red[4 * 64];

    const int tid = threadIdx.x;
    const int lane = tid & 63, wave = tid >> 6;
    const int m0 = blockIdx.x * TM;

    const __hip_bfloat16* gp[CH];
    #pragma unroll
    for (int c = 0; c < CH; c++) {
        int gid = c * 256 + tid;
        int row = gid >> 2, col = (gid & 3) * 8;
        gp[c] = (row < TM ? A + (size_t)(m0 + row) * K
                          : W + (size_t)(row - TM) * K) + col;
    }

    f32x4 acc[4][4] = {};
    const int fr = lane & 15, fkb = (lane >> 4) * 8;

    for (int k0 = 0; k0 < K; k0 += 32) {
        __syncthreads();
        #pragma unroll
        for (int c = 0; c < CH; c++)
            gld_lds16(gp[c] + k0, &ABs[(c * 256 + wave * 64) * 8]);
        asm volatile("s_waitcnt vmcnt(0)" ::: "memory");
        __syncthreads();
        bf16x8 a[4], b[4];
        #pragma unroll
        for (int i = 0; i < 4; i++)
            a[i] = *(const bf16x8*)&ABs[(i * 16 + fr) * 32 + fkb];
        #pragma unroll
        for (int j = 0; j < 4; j++)
            b[j] = *(const bf16x8*)&ABs[(TM + wave * 64 + j * 16 + fr) * 32 + fkb];
        #pragma unroll
        for (int i = 0; i < 4; i++)
            #pragma unroll
            for (int j = 0; j < 4; j++)
                acc[i][j] = __builtin_amdgcn_mfma_f32_16x16x32_bf16(a[i], b[j], acc[i][j], 0, 0, 0);
    }

    float p[4][4] = {};
    #pragma unroll
    for (int j = 0; j < 4; j++) {
        int n = wave * 64 + j * 16 + fr;
        float bv = b3[n], wv = w4[n];
        #pragma unroll
        for (int i = 0; i < 4; i++)
            #pragma unroll
            for (int r = 0; r < 4; r++)
                p[i][r] += fmaxf(acc[i][j][r] + bv, 0.f) * wv;
    }
    #pragma unroll
    for (int mask = 1; mask < 16; mask <<= 1)
        #pragma unroll
        for (int i = 0; i < 4; i++)
            #pragma unroll
            for (int r = 0; r < 4; r++)
                p[i][r] += __shfl_xor(p[i][r], mask, 64);
    const int fq = lane >> 4;
    if (fr == 0) {
        #pragma unroll
        for (int i = 0; i < 4; i++)
            #pragma unroll
            for (int r = 0; r < 4; r++)
                red[wave * 64 + i * 16 + fq * 4 + r] = p[i][r];
    }
    __syncthreads();
    if (tid < 64) {
        float s = red[tid] + red[64 + tid] + red[128 + tid] + red[192 + tid];
        out[m0 + tid] = 1.f / (1.f + expf(-(s + b4[0])));
    }
}

extern "C" void kernel_launch(void* const* d_in, const int* in_sizes, int n_in,
                              void* d_out, int out_size, void* d_ws, size_t ws_size,
                              hipStream_t stream) {
    const float* dense_x = (const float*)d_in[0];
    const int* sidx      = (const int*)d_in[1];
    const float* emb     = (const float*)d_in[2];
    const float* bw0 = (const float*)d_in[3];  const float* bb0 = (const float*)d_in[4];
    const float* bw1 = (const float*)d_in[5];  const float* bb1 = (const float*)d_in[6];
    const float* bw2 = (const float*)d_in[7];  const float* bb2 = (const float*)d_in[8];
    const float* tw0 = (const float*)d_in[9];  const float* tb0 = (const float*)d_in[10];
    const float* tw1 = (const float*)d_in[11]; const float* tb1 = (const float*)d_in[12];
    const float* tw2 = (const float*)d_in[13]; const float* tb2 = (const float*)d_in[14];
    const float* tw3 = (const float*)d_in[15]; const float* tb3 = (const float*)d_in[16];
    const float* tw4 = (const float*)d_in[17]; const float* tb4 = (const float*)d_in[18];
    float* out = (float*)d_out;

    char* ws = (char*)d_ws;
    size_t off = 0;
    auto alloc = [&](size_t bytes) {
        off = (off + 255) & ~(size_t)255;
        void* p = ws + off;
        off += bytes;
        return p;
    };
    __hip_bfloat16* Wb1 = (__hip_bfloat16*)alloc((size_t)256 * 512 * 2);
    __hip_bfloat16* Wb2 = (__hip_bfloat16*)alloc((size_t)128 * 256 * 2);
    __hip_bfloat16* Wt0 = (__hip_bfloat16*)alloc((size_t)1024 * 512 * 2);
    __hip_bfloat16* Wt1 = (__hip_bfloat16*)alloc((size_t)1024 * 1024 * 2);
    __hip_bfloat16* Wt2 = (__hip_bfloat16*)alloc((size_t)512 * 1024 * 2);
    __hip_bfloat16* Wt3 = (__hip_bfloat16*)alloc((size_t)256 * 512 * 2);
    __hip_bfloat16* bufA = (__hip_bfloat16*)alloc((size_t)B_SZ * 512 * 2);
    __hip_bfloat16* bufB = (__hip_bfloat16*)alloc((size_t)B_SZ * 256 * 2);
    __hip_bfloat16* Tbuf = (__hip_bfloat16*)alloc((size_t)B_SZ * TROW * 2);
    __hip_bfloat16* zbuf = (__hip_bfloat16*)alloc((size_t)B_SZ * 512 * 2);
    __hip_bfloat16* h0   = (__hip_bfloat16*)alloc((size_t)B_SZ * 1024 * 2);
    __hip_bfloat16* h1   = (__hip_bfloat16*)alloc((size_t)B_SZ * 1024 * 2);
    __hip_bfloat16* h2   = (__hip_bfloat16*)alloc((size_t)B_SZ * 512 * 2);

    CvtJobs J;
    auto setJob = [&](int i, const float* in, __hip_bfloat16* o, int N, int K, int Kp) {
        J.j[i] = {in, o, N, K, Kp};
    };
    setJob(0, bw1, Wb1, 256, 512, 512);
    setJob(1, bw2, Wb2, 128, 256, 256);
    setJob(2, tw0, Wt0, 1024, 479, 512);
    setJob(3, tw1, Wt1, 1024, 1024, 1024);
    setJob(4, tw2, Wt2, 512, 1024, 1024);
    setJob(5, tw3, Wt3, 256, 512, 512);
    J.start[0] = 0;
    for (int i = 0; i < 6; i++) J.start[i + 1] = J.start[i] + J.j[i].N * J.j[i].Kp;
    const int cvtB = (J.start[6] / 8 + 255) / 256;
    const int EMB_T = B_SZ / 4;   // blocks per table

    // L1: weight cvt || bot0 || emb(tables 0..8)
    k_pre_emb<<<cvtB + B_SZ / 4 + 9 * EMB_T, 256, 0, stream>>>(
        J, cvtB, dense_x, bw0, bb0, bufA, 0, sidx, emb, Tbuf);

    // L2: bot1 (256 tiles, 128x64) || emb(tables 9..16)
    k_gemm_emb<128, 64><<<256 + 8 * EMB_T, 256, 0, stream>>>(
        bufA, Wb1, bb1, bufB, 256 / 64, 512, 256, 256, 9, sidx, emb, Tbuf);

    // L3: bot2 (256 tiles, 64x64) -> Tbuf row 0 || emb(tables 17..25)
    k_gemm_emb<64, 64><<<256 + 9 * EMB_T, 256, 0, stream>>>(
        bufB, Wb2, bb2, Tbuf, 128 / 64, 256, TROW, 256, 17, sidx, emb, Tbuf);

    // L4: interaction -> z (B x 512, padded)
    k_int<<<B_SZ / 4, 256, 0, stream>>>(Tbuf, zbuf);

    // L5-L7: top MLP via 3-buffer counted-vmcnt pipeline (256 blocks = 1/CU each)
    gemm_pipe<256,  8><<<(B_SZ / 256) * (1024 / 128), 512, 0, stream>>>(zbuf, Wt0, tb0, h0, 1024 / 128, 1024);
    gemm_pipe<256, 16><<<(B_SZ / 256) * (1024 / 128), 512, 0, stream>>>(h0, Wt1, tb1, h1, 1024 / 128, 1024);
    gemm_pipe<128, 16><<<(B_SZ / 128) * ( 512 / 128), 512, 0, stream>>>(h1, Wt2, tb2, h2,  512 / 128,  512);

    // L8: fused top3 + final dot + sigmoid (128 blocks, TM=64)
    k_top3_fin<<<B_SZ / 64, 256, 0, stream>>>(h2, Wt3, tb3, tw4, tb4, out);
}

// Round 15
// 270.474 us; speedup vs baseline: 1.1239x; 1.0161x over previous
//
#include <hip/hip_runtime.h>
#include <hip/hip_bf16.h>
#include <cstdint>

typedef __attribute__((ext_vector_type(8))) short bf16x8;
typedef __attribute__((ext_vector_type(4))) short bf16x4;
typedef __attribute__((ext_vector_type(4))) float f32x4;

#define B_SZ 8192
#define TROW 3456   // 27*128, per-sample stride of T buffer (bf16 elems)

__device__ __forceinline__ void gld_lds16(const void* g, void* l) {
    __builtin_amdgcn_global_load_lds(
        (const __attribute__((address_space(1))) unsigned int*)g,
        (__attribute__((address_space(3))) unsigned int*)l, 16, 0, 0);
}

__device__ __forceinline__ short f2bf_bits(float v) {
    return __builtin_bit_cast(short, __float2bfloat16(v));
}

template<int N> __device__ __forceinline__ void waitcnt_vm() {
    if constexpr (N == 0) asm volatile("s_waitcnt vmcnt(0)" ::: "memory");
    else if constexpr (N == 4) asm volatile("s_waitcnt vmcnt(4)" ::: "memory");
    else if constexpr (N == 6) asm volatile("s_waitcnt vmcnt(6)" ::: "memory");
}

// ---------------- weight cvt (8 elems/thread) ----------------
struct CvtJob { const float* in; __hip_bfloat16* out; int N, K, Kp; };
struct CvtJobs { CvtJob j[6]; int start[7]; };   // starts in ELEMENTS (all sizes %8==0)

__device__ __forceinline__ void cvt_dev8(int lb, int tid, const CvtJobs& J) {
    int chunk = lb * 256 + tid;
    int e = chunk * 8;
    if (e >= J.start[6]) return;
    int k = 0;
    #pragma unroll
    for (int i = 1; i < 6; i++) if (e >= J.start[i]) k = i;
    const CvtJob& job = J.j[k];
    int local = e - J.start[k];
    float v[8];
    if (job.K == job.Kp) {
        const float4* p = (const float4*)(job.in + local);
        float4 a = p[0], b = p[1];
        v[0]=a.x; v[1]=a.y; v[2]=a.z; v[3]=a.w; v[4]=b.x; v[5]=b.y; v[6]=b.z; v[7]=b.w;
    } else {
        int n = local / job.Kp, kk = local - n * job.Kp;
        #pragma unroll
        for (int i = 0; i < 8; i++)
            v[i] = (kk + i < job.K) ? job.in[(size_t)n * job.K + kk + i] : 0.f;
    }
    bf16x8 o;
    #pragma unroll
    for (int i = 0; i < 8; i++)
        o[i] = f2bf_bits(v[i]);
    *(bf16x8*)(job.out + local) = o;
}

// ---------------- bot0 fp32 (K=13) ----------------
__device__ __forceinline__ void bot0_dev(int lb, int tid, const float* __restrict__ x,
    const float* __restrict__ w, const float* __restrict__ bias,
    __hip_bfloat16* __restrict__ o, float* xs) {
    int m0 = lb * 4;
    if (tid < 52) xs[tid] = x[(size_t)m0 * 13 + tid];
    __syncthreads();
    for (int c = tid; c < 512; c += 256) {
        const float* wr = w + (size_t)c * 13;
        float bv = bias[c];
        #pragma unroll
        for (int r = 0; r < 4; r++) {
            float s = bv;
            #pragma unroll
            for (int k = 0; k < 13; k++) s += xs[r * 13 + k] * wr[k];
            o[(size_t)(m0 + r) * 512 + c] = __float2bfloat16(fmaxf(s, 0.f));
        }
    }
}

// ---------------- embedding gather-sum (16B/lane, table slice from t0) ----------------
__device__ __forceinline__ void emb_dev(int lb, int tid, int t0,
    const int* __restrict__ idx, const float* __restrict__ tab,
    __hip_bfloat16* __restrict__ T) {
    int lane = tid & 63, wv = tid >> 6;
    int p = lb * 4 + wv;
    int t = t0 + (p >> 13);
    int b = p & 8191;
    const int* ip = idx + (size_t)t * 81920 + b * 10;
    const float* tb = tab + (size_t)t * 100000 * 128;
    int half = lane >> 5, l32 = lane & 31;
    float4 s = {0.f, 0.f, 0.f, 0.f};
    #pragma unroll
    for (int j = 0; j < 10; j += 2) {
        int r = ip[j + half];
        float4 v = ((const float4*)(tb + (size_t)r * 128))[l32];
        s.x += v.x; s.y += v.y; s.z += v.z; s.w += v.w;
    }
    s.x += __shfl_xor(s.x, 32, 64);
    s.y += __shfl_xor(s.y, 32, 64);
    s.z += __shfl_xor(s.z, 32, 64);
    s.w += __shfl_xor(s.w, 32, 64);
    if (half == 0) {
        bf16x4 o;
        o[0] = f2bf_bits(s.x); o[1] = f2bf_bits(s.y);
        o[2] = f2bf_bits(s.z); o[3] = f2bf_bits(s.w);
        ((bf16x4*)(T + (size_t)b * TROW + (1 + t) * 128))[l32] = o;
    }
}

// ---------------- GEMM device core: BK=64, XOR-swizzled LDS (R10, proven) ----------------
template<int TM, int TN, int WM, int WN>
__device__ __forceinline__ void gemm_dev(int tileId, int nTiles, int nbx, int tid,
    const __hip_bfloat16* __restrict__ A, const __hip_bfloat16* __restrict__ W,
    const float* __restrict__ bias, __hip_bfloat16* __restrict__ C,
    int K, int ldc, __hip_bfloat16* ABs) {
    constexpr int BK = 64;
    constexpr int ROWS = TM + TN;
    constexpr int CH = ROWS * BK / 2048;
    constexpr int MI = TM / WM / 16;
    constexpr int NI = TN / WN / 16;

    int swz = tileId;
    if ((nTiles & 7) == 0) {
        int q = nTiles >> 3;
        swz = (tileId & 7) * q + (tileId >> 3);
    }
    const int by = swz / nbx, bx = swz - by * nbx;
    const int m0 = by * TM, n0 = bx * TN;

    const int lane = tid & 63, wave = tid >> 6;
    const int wmI = wave / WN, wnI = wave % WN;

    const __hip_bfloat16* gp[CH];
    #pragma unroll
    for (int c = 0; c < CH; c++) {
        int gid = c * 256 + tid;
        int row = gid >> 3;
        int cs = ((gid & 7) ^ (row & 7)) * 8;
        gp[c] = (row < TM ? A + (size_t)(m0 + row) * K
                          : W + (size_t)(n0 + row - TM) * K) + cs;
    }

    f32x4 acc[MI][NI] = {};
    const int fr = lane & 15, hi = lane >> 4;

    for (int k0 = 0; k0 < K; k0 += BK) {
        __syncthreads();
        #pragma unroll
        for (int c = 0; c < CH; c++)
            gld_lds16(gp[c] + k0, &ABs[(c * 256 + wave * 64) * 8]);
        asm volatile("s_waitcnt vmcnt(0)" ::: "memory");
        __syncthreads();
        #pragma unroll
        for (int ks = 0; ks < 2; ks++) {
            bf16x8 a[MI], b[NI];
            #pragma unroll
            for (int i = 0; i < MI; i++) {
                int row = wmI * (TM / WM) + i * 16 + fr;
                a[i] = *(const bf16x8*)&ABs[row * BK + (((ks * 4 + hi) ^ (row & 7)) * 8)];
            }
            #pragma unroll
            for (int j = 0; j < NI; j++) {
                int row = TM + wnI * (TN / WN) + j * 16 + fr;
                b[j] = *(const bf16x8*)&ABs[row * BK + (((ks * 4 + hi) ^ (row & 7)) * 8)];
            }
            #pragma unroll
            for (int i = 0; i < MI; i++)
                #pragma unroll
                for (int j = 0; j < NI; j++)
                    acc[i][j] = __builtin_amdgcn_mfma_f32_16x16x32_bf16(a[i], b[j], acc[i][j], 0, 0, 0);
        }
    }

    const int fq = hi;
    #pragma unroll
    for (int i = 0; i < MI; i++) {
        #pragma unroll
        for (int j = 0; j < NI; j++) {
            int n = n0 + wnI * (TN / WN) + j * 16 + fr;
            float bv = bias[n];
            #pragma unroll
            for (int r = 0; r < 4; r++) {
                int m = m0 + wmI * (TM / WM) + i * 16 + fq * 4 + r;
                C[(size_t)m * ldc + n] = __float2bfloat16(fmaxf(acc[i][j][r] + bv, 0.f));
            }
        }
    }
}

template<int TM, int TN, int WM, int WN>
__global__ __launch_bounds__(256) void gemm_k(const __hip_bfloat16* A, const __hip_bfloat16* W,
                                              const float* bias, __hip_bfloat16* C,
                                              int nbx, int K, int ldc) {
    __shared__ __align__(16) __hip_bfloat16 ABs[(TM + TN) * 64];
    gemm_dev<TM, TN, WM, WN>(blockIdx.x, gridDim.x, nbx, threadIdx.x, A, W, bias, C, K, ldc, ABs);
}

// ---------------- pipelined GEMM: BM x 128, BK=64, 512 thr, 3-buffer counted-vmcnt ----------------
// Iter t: compute K-tile t from buf[t%3]; stage tile t+2 into buf[(t+2)%3] (freed at end of
// iter t-1); iter-end vmcnt(R) retires tile t+1's R per-thread loads; raw s_barrier
// collectivizes per-wave guarantees. vmcnt(0) only in the final 2 iterations.
// (No mid-phase barrier: phase A reads buf[t%3], phase B stages into (t+2)%3 — disjoint.)
template<int BM, int KTILES>
__global__ __launch_bounds__(512) void gemm_pipe(const __hip_bfloat16* __restrict__ A,
                                                 const __hip_bfloat16* __restrict__ W,
                                                 const float* __restrict__ bias,
                                                 __hip_bfloat16* __restrict__ C,
                                                 int nbx, int ldc) {
    constexpr int K = KTILES * 64;
    constexpr int ROWS = BM + 128;
    constexpr int R = ROWS / 64;           // staging rounds per K-tile (6 for BM=256, 4 for BM=128)
    constexpr int MI = BM / 2 / 16;        // per-wave M fragments (8 or 4)
    __shared__ __align__(16) __hip_bfloat16 ABs[3 * ROWS * 64];
    const int tid = threadIdx.x;
    const int lane = tid & 63, wave = tid >> 6;
    const int wm = wave >> 2, wn = wave & 3;        // 2M x 4N wave grid

    int swz = blockIdx.x;                            // grid %8 == 0
    { int q = (int)gridDim.x >> 3; swz = (swz & 7) * q + (swz >> 3); }
    const int by = swz / nbx, bx = swz - by * nbx;
    const int m0 = by * BM, n0 = bx * 128;

    // staging: R rounds x 512 threads x 16B per K-tile (A BM rows + W 128 rows)
    const __hip_bfloat16* gp[R];
    #pragma unroll
    for (int r = 0; r < R; r++) {
        int gid = r * 512 + tid;
        int row = gid >> 3;                          // 8 x 16B chunks per 64-elem row
        int cs = ((gid & 7) ^ (row & 7)) * 8;        // pre-swizzled source column
        gp[r] = (row < BM ? A + (size_t)(m0 + row) * K
                          : W + (size_t)(n0 + row - BM) * K) + cs;
    }
    auto stageH = [&](int s, int t, int h) {         // half-tile staging (R/2 rounds)
        __hip_bfloat16* dst = &ABs[s * ROWS * 64];
        #pragma unroll
        for (int r = h * (R / 2); r < (h + 1) * (R / 2); r++)
            gld_lds16(gp[r] + t * 64, &dst[(r * 512 + wave * 64) * 8]);
    };

    f32x4 acc[MI][2] = {};
    const int fr = lane & 15, hi = lane >> 4;

    // prologue: stage tiles 0 and 1
    stageH(0, 0, 0); stageH(0, 0, 1);
    stageH(1, 1, 0); stageH(1, 1, 1);
    waitcnt_vm<R>();                     // tile 0 landed (tile 1's R loads outstanding)
    __builtin_amdgcn_s_barrier();

    for (int t = 0; t < KTILES; ++t) {
        const __hip_bfloat16* buf = &ABs[(t % 3) * ROWS * 64];
        const bool pf = (t + 2) < KTILES;
        const int s2 = (t + 2) % 3;

        // phase A: issue half the prefetch, compute kslab 0
        if (pf) stageH(s2, t + 2, 0);
        {
            bf16x8 a[MI], b[2];
            #pragma unroll
            for (int i = 0; i < MI; i++) {
                int row = wm * (BM / 2) + i * 16 + fr;
                a[i] = *(const bf16x8*)&buf[row * 64 + ((hi ^ (row & 7)) * 8)];
            }
            #pragma unroll
            for (int j = 0; j < 2; j++) {
                int row = BM + wn * 32 + j * 16 + fr;
                b[j] = *(const bf16x8*)&buf[row * 64 + ((hi ^ (row & 7)) * 8)];
            }
            __builtin_amdgcn_s_setprio(1);
            #pragma unroll
            for (int i = 0; i < MI; i++)
                #pragma unroll
                for (int j = 0; j < 2; j++)
                    acc[i][j] = __builtin_amdgcn_mfma_f32_16x16x32_bf16(a[i], b[j], acc[i][j], 0, 0, 0);
            __builtin_amdgcn_s_setprio(0);
        }

        // phase B: issue rest of prefetch, compute kslab 1 (no barrier needed between phases)
        if (pf) stageH(s2, t + 2, 1);
        {
            bf16x8 a[MI], b[2];
            #pragma unroll
            for (int i = 0; i < MI; i++) {
                int row = wm * (BM / 2) + i * 16 + fr;
                a[i] = *(const bf16x8*)&buf[row * 64 + (((4 + hi) ^ (row & 7)) * 8)];
            }
            #pragma unroll
            for (int j = 0; j < 2; j++) {
                int row = BM + wn * 32 + j * 16 + fr;
                b[j] = *(const bf16x8*)&buf[row * 64 + (((4 + hi) ^ (row & 7)) * 8)];
            }
            __builtin_amdgcn_s_setprio(1);
            #pragma unroll
            for (int i = 0; i < MI; i++)
                #pragma unroll
                for (int j = 0; j < 2; j++)
                    acc[i][j] = __builtin_amdgcn_mfma_f32_16x16x32_bf16(a[i], b[j], acc[i][j], 0, 0, 0);
            __builtin_amdgcn_s_setprio(0);
        }
        // iteration end: tile t+1 must be landed before next iter reads it
        if (pf) waitcnt_vm<R>();
        else    waitcnt_vm<0>();
        __builtin_amdgcn_s_barrier();
    }

    // epilogue
    #pragma unroll
    for (int i = 0; i < MI; i++) {
        #pragma unroll
        for (int j = 0; j < 2; j++) {
            int n = n0 + wn * 32 + j * 16 + fr;
            float bv = bias[n];
            #pragma unroll
            for (int r = 0; r < 4; r++) {
                int m = m0 + wm * (BM / 2) + i * 16 + hi * 4 + r;
                C[(size_t)m * ldc + n] = __float2bfloat16(fmaxf(acc[i][j][r] + bv, 0.f));
            }
        }
    }
}

// L1: cvt || bot0 || emb(tables t0..)
__global__ __launch_bounds__(256) void k_pre_emb(CvtJobs J, int cvtB,
    const float* dx, const float* w0, const float* b0, __hip_bfloat16* bufA,
    int t0, const int* sidx, const float* tab, __hip_bfloat16* T) {
    __shared__ float xs[64];
    int blk = blockIdx.x, tid = threadIdx.x;
    if (blk < cvtB) { cvt_dev8(blk, tid, J); return; }
    blk -= cvtB;
    if (blk < B_SZ / 4) { bot0_dev(blk, tid, dx, w0, b0, bufA, xs); return; }
    emb_dev(blk - B_SZ / 4, tid, t0, sidx, tab, T);
}

// gemm || emb(tables t0..)
template<int TM, int TN>
__global__ __launch_bounds__(256) void k_gemm_emb(const __hip_bfloat16* A, const __hip_bfloat16* W,
    const float* bias, __hip_bfloat16* C, int nbx, int K, int ldc, int gB,
    int t0, const int* sidx, const float* tab, __hip_bfloat16* T) {
    __shared__ __align__(16) __hip_bfloat16 ABs[(TM + TN) * 64];
    if (blockIdx.x < gB)
        gemm_dev<TM, TN, 2, 2>(blockIdx.x, gB, nbx, threadIdx.x, A, W, bias, C, K, ldc, ABs);
    else
        emb_dev(blockIdx.x - gB, threadIdx.x, t0, sidx, tab, T);
}

// ---------------- interaction (LDS-free): 4 samples/block ----------------
__global__ __launch_bounds__(256) void k_int(const __hip_bfloat16* __restrict__ T,
                                             __hip_bfloat16* __restrict__ z) {
    int lane = threadIdx.x & 63, wave = threadIdx.x >> 6;
    int b = blockIdx.x * 4 + wave;
    const __hip_bfloat16* Tb = T + (size_t)b * TROW;

    const int fr = lane & 15, fkb = (lane >> 4) * 8;
    bf16x8 fr2[2][4];
    #pragma unroll
    for (int mi = 0; mi < 2; mi++)
        #pragma unroll
        for (int kt = 0; kt < 4; kt++)
            fr2[mi][kt] = *(const bf16x8*)&Tb[(mi * 16 + fr) * 128 + kt * 32 + fkb];

    f32x4 acc[2][2] = {};
    #pragma unroll
    for (int kt = 0; kt < 4; kt++)
        #pragma unroll
        for (int mi = 0; mi < 2; mi++)
            #pragma unroll
            for (int ni = 0; ni < 2; ni++)
                acc[mi][ni] = __builtin_amdgcn_mfma_f32_16x16x32_bf16(fr2[mi][kt], fr2[ni][kt], acc[mi][ni], 0, 0, 0);

    __hip_bfloat16* zb = z + (size_t)b * 512;
    ((unsigned*)zb)[lane] = ((const unsigned*)Tb)[lane];       // copy x row (128 bf16)
    if (lane < 33) zb[479 + lane] = __float2bfloat16(0.f);     // pad cols 479..511
    const int fq = lane >> 4;
    #pragma unroll
    for (int mi = 0; mi < 2; mi++)
        #pragma unroll
        for (int ni = 0; ni < 2; ni++)
            #pragma unroll
            for (int r = 0; r < 4; r++) {
                int m = mi * 16 + fq * 4 + r;
                int n = ni * 16 + fr;
                if (m < 27 && n < 27 && m < n) {
                    int p = m * 26 - (m * (m - 1)) / 2 + (n - m - 1);
                    zb[128 + p] = __float2bfloat16(acc[mi][ni][r]);
                }
            }
}

// ---------------- fused top3+final: TM=32 rows/block (256 blocks = 1/CU), K=512, BK=32 ----------------
// LDS rows: 0..255 = W (256 x 512), 256..287 = A rows m0..m0+31. Epilogue unchanged from R10 style.
__global__ __launch_bounds__(256) void k_top3_fin(const __hip_bfloat16* __restrict__ A,
                                                  const __hip_bfloat16* __restrict__ W,
                                                  const float* __restrict__ b3,
                                                  const float* __restrict__ w4,
                                                  const float* __restrict__ b4,
                                                  float* __restrict__ out) {
    constexpr int TM = 32, TN = 256, K = 512;
    constexpr int ROWS = TM + TN;           // 288
    __shared__ __align__(16) __hip_bfloat16 ABs[ROWS * 32];
    __shared__ float red[4 * 32];

    const int tid = threadIdx.x;
    const int lane = tid & 63, wave = tid >> 6;   // wnI = wave (WM=1, WN=4)
    const int m0 = blockIdx.x * TM;

    // 16B chunks: 288 rows x 4 chunks = 1152; 5 chunk-passes, last one quarter-masked
    const __hip_bfloat16* gp[5];
    #pragma unroll
    for (int c = 0; c < 5; c++) {
        int gid = c * 256 + tid;
        int row = gid >> 2, col = (gid & 3) * 8;
        if (gid < 1152)
            gp[c] = (row < TN ? W + (size_t)row * K
                              : A + (size_t)(m0 + row - TN) * K) + col;
        else gp[c] = nullptr;
    }

    f32x4 acc[2][4] = {};
    const int fr = lane & 15, fkb = (lane >> 4) * 8;

    for (int k0 = 0; k0 < K; k0 += 32) {
        __syncthreads();
        #pragma unroll
        for (int c = 0; c < 5; c++)
            if (gp[c])
                gld_lds16(gp[c] + k0, &ABs[(c * 256 + wave * 64) * 8]);
        asm volatile("s_waitcnt vmcnt(0)" ::: "memory");
        __syncthreads();
        bf16x8 a[2], b[4];
        #pragma unroll
        for (int i = 0; i < 2; i++)
            a[i] = *(const bf16x8*)&ABs[(TN + i * 16 + fr) * 32 + fkb];
        #pragma unroll
        for (int j = 0; j < 4; j++)
            b[j] = *(const bf16x8*)&ABs[(wave * 64 + j * 16 + fr) * 32 + fkb];
        #pragma unroll
        for (int i = 0; i < 2; i++)
            #pragma unroll
            for (int j = 0; j < 4; j++)
                acc[i][j] = __builtin_amdgcn_mfma_f32_16x16x32_bf16(a[i], b[j], acc[i][j], 0, 0, 0);
    }

    // epilogue: per-lane partial of sum_n relu(acc + b3[n]) * w4[n]
    float p[2][4] = {};   // [i][r]
    #pragma unroll
    for (int j = 0; j < 4; j++) {
        int n = wave * 64 + j * 16 + fr;
        float bv = b3[n], wv = w4[n];
        #pragma unroll
        for (int i = 0; i < 2; i++)
            #pragma unroll
            for (int r = 0; r < 4; r++)
                p[i][r] += fmaxf(acc[i][j][r] + bv, 0.f) * wv;
    }
    #pragma unroll
    for (int mask = 1; mask < 16; mask <<= 1)
        #pragma unroll
        for (int i = 0; i < 2; i++)
            #pragma unroll
            for (int r = 0; r < 4; r++)
                p[i][r] += __shfl_xor(p[i][r], mask, 64);
    const int fq = lane >> 4;
    if (fr == 0) {
        #pragma unroll
        for (int i = 0; i < 2; i++)
            #pragma unroll
            for (int r = 0; r < 4; r++)
                red[wave * 32 + i * 16 + fq * 4 + r] = p[i][r];
    }
    __syncthreads();
    if (tid < 32) {
        float s = red[tid] + red[32 + tid] + red[64 + tid] + red[96 + tid];
        out[m0 + tid] = 1.f / (1.f + expf(-(s + b4[0])));
    }
}

extern "C" void kernel_launch(void* const* d_in, const int* in_sizes, int n_in,
                              void* d_out, int out_size, void* d_ws, size_t ws_size,
                              hipStream_t stream) {
    const float* dense_x = (const float*)d_in[0];
    const int* sidx      = (const int*)d_in[1];
    const float* emb     = (const float*)d_in[2];
    const float* bw0 = (const float*)d_in[3];  const float* bb0 = (const float*)d_in[4];
    const float* bw1 = (const float*)d_in[5];  const float* bb1 = (const float*)d_in[6];
    const float* bw2 = (const float*)d_in[7];  const float* bb2 = (const float*)d_in[8];
    const float* tw0 = (const float*)d_in[9];  const float* tb0 = (const float*)d_in[10];
    const float* tw1 = (const float*)d_in[11]; const float* tb1 = (const float*)d_in[12];
    const float* tw2 = (const float*)d_in[13]; const float* tb2 = (const float*)d_in[14];
    const float* tw3 = (const float*)d_in[15]; const float* tb3 = (const float*)d_in[16];
    const float* tw4 = (const float*)d_in[17]; const float* tb4 = (const float*)d_in[18];
    float* out = (float*)d_out;

    char* ws = (char*)d_ws;
    size_t off = 0;
    auto alloc = [&](size_t bytes) {
        off = (off + 255) & ~(size_t)255;
        void* p = ws + off;
        off += bytes;
        return p;
    };
    __hip_bfloat16* Wb1 = (__hip_bfloat16*)alloc((size_t)256 * 512 * 2);
    __hip_bfloat16* Wb2 = (__hip_bfloat16*)alloc((size_t)128 * 256 * 2);
    __hip_bfloat16* Wt0 = (__hip_bfloat16*)alloc((size_t)1024 * 512 * 2);
    __hip_bfloat16* Wt1 = (__hip_bfloat16*)alloc((size_t)1024 * 1024 * 2);
    __hip_bfloat16* Wt2 = (__hip_bfloat16*)alloc((size_t)512 * 1024 * 2);
    __hip_bfloat16* Wt3 = (__hip_bfloat16*)alloc((size_t)256 * 512 * 2);
    __hip_bfloat16* bufA = (__hip_bfloat16*)alloc((size_t)B_SZ * 512 * 2);
    __hip_bfloat16* bufB = (__hip_bfloat16*)alloc((size_t)B_SZ * 256 * 2);
    __hip_bfloat16* Tbuf = (__hip_bfloat16*)alloc((size_t)B_SZ * TROW * 2);
    __hip_bfloat16* zbuf = (__hip_bfloat16*)alloc((size_t)B_SZ * 512 * 2);
    __hip_bfloat16* h0   = (__hip_bfloat16*)alloc((size_t)B_SZ * 1024 * 2);
    __hip_bfloat16* h1   = (__hip_bfloat16*)alloc((size_t)B_SZ * 1024 * 2);
    __hip_bfloat16* h2   = (__hip_bfloat16*)alloc((size_t)B_SZ * 512 * 2);

    CvtJobs J;
    auto setJob = [&](int i, const float* in, __hip_bfloat16* o, int N, int K, int Kp) {
        J.j[i] = {in, o, N, K, Kp};
    };
    setJob(0, bw1, Wb1, 256, 512, 512);
    setJob(1, bw2, Wb2, 128, 256, 256);
    setJob(2, tw0, Wt0, 1024, 479, 512);
    setJob(3, tw1, Wt1, 1024, 1024, 1024);
    setJob(4, tw2, Wt2, 512, 1024, 1024);
    setJob(5, tw3, Wt3, 256, 512, 512);
    J.start[0] = 0;
    for (int i = 0; i < 6; i++) J.start[i + 1] = J.start[i] + J.j[i].N * J.j[i].Kp;
    const int cvtB = (J.start[6] / 8 + 255) / 256;
    const int EMB_T = B_SZ / 4;   // blocks per table

    // L1: weight cvt || bot0 || emb(tables 0..8)
    k_pre_emb<<<cvtB + B_SZ / 4 + 9 * EMB_T, 256, 0, stream>>>(
        J, cvtB, dense_x, bw0, bb0, bufA, 0, sidx, emb, Tbuf);

    // L2: bot1 (256 tiles, 128x64) || emb(tables 9..16)
    k_gemm_emb<128, 64><<<256 + 8 * EMB_T, 256, 0, stream>>>(
        bufA, Wb1, bb1, bufB, 256 / 64, 512, 256, 256, 9, sidx, emb, Tbuf);

    // L3: bot2 (256 tiles, 64x64) -> Tbuf row 0 || emb(tables 17..25)
    k_gemm_emb<64, 64><<<256 + 9 * EMB_T, 256, 0, stream>>>(
        bufB, Wb2, bb2, Tbuf, 128 / 64, 256, TROW, 256, 17, sidx, emb, Tbuf);

    // L4: interaction -> z (B x 512, padded)
    k_int<<<B_SZ / 4, 256, 0, stream>>>(Tbuf, zbuf);

    // L5-L7: top MLP via 3-buffer counted-vmcnt pipeline (256 blocks = 1/CU each)
    gemm_pipe<256,  8><<<(B_SZ / 256) * (1024 / 128), 512, 0, stream>>>(zbuf, Wt0, tb0, h0, 1024 / 128, 1024);
    gemm_pipe<256, 16><<<(B_SZ / 256) * (1024 / 128), 512, 0, stream>>>(h0, Wt1, tb1, h1, 1024 / 128, 1024);
    gemm_pipe<128, 16><<<(B_SZ / 128) * ( 512 / 128), 512, 0, stream>>>(h1, Wt2, tb2, h2,  512 / 128,  512);

    // L8: fused top3 + final dot + sigmoid (256 blocks = 1/CU, TM=32)
    k_top3_fin<<<B_SZ / 32, 256, 0, stream>>>(h2, Wt3, tb3, tw4, tb4, out);
}